// Round 3
// baseline (181.043 us; speedup 1.0000x reference)
//
#include <hip/hip_runtime.h>

#define EMBED 1024
#define NTOK  4096
#define MARGIN 256.0f   // i8 cheap-logit error sigma ~22; 2*5.5sigma + window
#define KC     8        // candidate slots per (row, wave-tile)
#define CAP    128      // final per-row candidate cap

// i8 scales: Xi8 = round(X * 127/5), Qi8 = round(Q' * 127/8192)
#define SX_INV 25.4f
#define SQ_INV 0.0155029296875f
#define SCLOGIT 0.07936198f   // (8192/127)*(5/127)/32

typedef short  s16x8 __attribute__((ext_vector_type(8)));
typedef float  f32x4 __attribute__((ext_vector_type(4)));
typedef int    i32x4 __attribute__((ext_vector_type(4)));

// ---- bf16 helpers (RNE) ----------------------------------------------------
__device__ __forceinline__ unsigned short f2bf(float f) {
    unsigned int u = __float_as_uint(f);
    u = (u + 0x7FFFu + ((u >> 16) & 1u)) >> 16;
    return (unsigned short)u;
}
__device__ __forceinline__ float bf2f(unsigned short h) {
    return __uint_as_float(((unsigned int)h) << 16);
}

// ---- async 16B global->LDS -------------------------------------------------
__device__ __forceinline__ void async16(const void* g, void* l) {
    __builtin_amdgcn_global_load_lds(
        (const __attribute__((address_space(1))) unsigned int*)g,
        (__attribute__((address_space(3))) unsigned int*)l, 16, 0, 0);
}

// Stage ROWS x 64-byte rows (row-major, swizzled 16B chunks) into LDS.
// ld in BYTES. 4-wave (256-thread) version.
template<int ROWS>
__device__ __forceinline__ void stage_rows(const char* __restrict__ g,
                                           int ld, char* lds, int wave, int lane) {
#pragma unroll
    for (int r = 0; r < ROWS / 64; ++r) {
        const int row0 = (wave * (ROWS / 64) + r) * 16;   // wave-uniform
        const int r_loc = lane >> 2;
        const int kc = (lane - (lane >> 3)) & 3;          // (slot - r_loc/2) & 3
        const char* gp = g + (size_t)(row0 + r_loc) * ld + kc * 16;
        char* lp = lds + row0 * 64;                       // wave-uniform base
        async16(gp, lp);
    }
}

__device__ __forceinline__ int frag_slot(int row, int kc) {
    return (kc + ((row & 15) >> 1)) & 3;
}
__device__ __forceinline__ s16x8 frag_bf16(const char* lds, int row, int kc) {
    return *(const s16x8*)(lds + row * 64 + frag_slot(row, kc) * 16);
}
__device__ __forceinline__ i32x4 frag_i8(const char* lds, int row, int kc) {
    return *(const i32x4*)(lds + row * 64 + frag_slot(row, kc) * 16);
}

// convert 8 fp32 -> bf16 hi/lo and store 16B each to LDS
__device__ __forceinline__ void cvt8_write(float4 a, float4 b, char* hw, char* lw) {
    float fs[8] = {a.x, a.y, a.z, a.w, b.x, b.y, b.z, b.w};
    s16x8 hv, lv;
#pragma unroll
    for (int e = 0; e < 8; ++e) {
        const unsigned short h = f2bf(fs[e]);
        hv[e] = (short)h;
        lv[e] = (short)f2bf(fs[e] - bf2f(h));
    }
    *(s16x8*)hw = hv;
    *(s16x8*)lw = lv;
}

// ---------------------------------------------------------------------------
// prep: W -> bf16 hi/lo splits, X -> i8 only (X hi/lo no longer materialized;
// the Qf GEMM consumes fp32 X directly). 6144 blocks x 256 threads.
// ---------------------------------------------------------------------------
__global__ __launch_bounds__(256) void prep(
        const float4* __restrict__ X, const float4* __restrict__ Wq,
        const float4* __restrict__ Wk, char4* __restrict__ Xi8,
        ushort4* __restrict__ Wqhi, ushort4* __restrict__ Wqlo,
        ushort4* __restrict__ Wkhi, ushort4* __restrict__ Wklo) {
    const int NW4 = EMBED * EMBED / 4;                    // 262144
    const int n = blockIdx.x * 256 + threadIdx.x;
    if (n < 2 * NW4) {
        const float4* src;
        ushort4 *hi, *lo;
        int idx;
        if (n < NW4) { src = Wq; hi = Wqhi; lo = Wqlo; idx = n; }
        else         { src = Wk; hi = Wkhi; lo = Wklo; idx = n - NW4; }
        const float4 v = src[idx];
        ushort4 h, l;
        h.x = f2bf(v.x); l.x = f2bf(v.x - bf2f(h.x));
        h.y = f2bf(v.y); l.y = f2bf(v.y - bf2f(h.y));
        h.z = f2bf(v.z); l.z = f2bf(v.z - bf2f(h.z));
        h.w = f2bf(v.w); l.w = f2bf(v.w - bf2f(h.w));
        hi[idx] = h; lo[idx] = l;
    } else {
        const int idx = n - 2 * NW4;                      // over NTOK*EMBED/4
        const float4 v = X[idx];
        char4 c;
        c.x = (signed char)(int)rintf(fminf(fmaxf(v.x * SX_INV, -127.f), 127.f));
        c.y = (signed char)(int)rintf(fminf(fmaxf(v.y * SX_INV, -127.f), 127.f));
        c.z = (signed char)(int)rintf(fminf(fmaxf(v.z * SX_INV, -127.f), 127.f));
        c.w = (signed char)(int)rintf(fminf(fmaxf(v.w * SX_INV, -127.f), 127.f));
        Xi8[idx] = c;
    }
}

// ---------------------------------------------------------------------------
// Split-K=4 T-partial GEMM. T = Wk @ Wq^T, 3-pass split bf16, 64x64 tile,
// K-slice = 256 per z. Partials to Cpart[z] (fp32, no atomics).
// grid (16,16,4), 256 threads.
// ---------------------------------------------------------------------------
__global__ __launch_bounds__(256) void t_gemm(
        const unsigned short* __restrict__ Ahi, const unsigned short* __restrict__ Alo,
        const unsigned short* __restrict__ Bhi, const unsigned short* __restrict__ Blo,
        float* __restrict__ Cpart)
{
    constexpr int BM = 64, BN = 64, NCH = 2;
    __shared__ __align__(16) char As_hi[BM * 64 * NCH];
    __shared__ __align__(16) char Bs_hi[BN * 64 * NCH];
    __shared__ __align__(16) char As_lo[BM * 64 * NCH];
    __shared__ __align__(16) char Bs_lo[BN * 64 * NCH];

    const int t = threadIdx.x;
    const int z = blockIdx.z;
    const int lane = t & 63, wave = t >> 6;
    const int wm = wave >> 1, wn = wave & 1;
    const int m0 = blockIdx.y * BM, n0 = blockIdx.x * BN;

    f32x4 acc[2][2];
#pragma unroll
    for (int i = 0; i < 2; ++i)
#pragma unroll
        for (int j = 0; j < 2; ++j)
#pragma unroll
            for (int r = 0; r < 4; ++r) acc[i][j][r] = 0.f;

    const char* ah_g = (const char*)(Ahi + (size_t)m0 * EMBED);
    const char* bh_g = (const char*)(Bhi + (size_t)n0 * EMBED);
    const char* al_g = (const char*)(Alo + (size_t)m0 * EMBED);
    const char* bl_g = (const char*)(Blo + (size_t)n0 * EMBED);

    const int kc = lane >> 4;
    const int rr = lane & 15;
    const int kbeg = z * 256;

    for (int k0 = kbeg; k0 < kbeg + 256; k0 += 32 * NCH) {
#pragma unroll
        for (int c = 0; c < NCH; ++c) {
            const int kb = (k0 + 32 * c) * 2;
            stage_rows<BM>(ah_g + kb, EMBED * 2, As_hi + c * BM * 64, wave, lane);
            stage_rows<BN>(bh_g + kb, EMBED * 2, Bs_hi + c * BN * 64, wave, lane);
            stage_rows<BM>(al_g + kb, EMBED * 2, As_lo + c * BM * 64, wave, lane);
            stage_rows<BN>(bl_g + kb, EMBED * 2, Bs_lo + c * BN * 64, wave, lane);
        }
        __syncthreads();

#pragma unroll
        for (int c = 0; c < NCH; ++c) {
            s16x8 ah[2], bh[2], al[2], bl[2];
#pragma unroll
            for (int i = 0; i < 2; ++i)
                ah[i] = frag_bf16(As_hi + c * BM * 64, wm * 32 + i * 16 + rr, kc);
#pragma unroll
            for (int j = 0; j < 2; ++j)
                bh[j] = frag_bf16(Bs_hi + c * BN * 64, wn * 32 + j * 16 + rr, kc);
#pragma unroll
            for (int i = 0; i < 2; ++i)
                al[i] = frag_bf16(As_lo + c * BM * 64, wm * 32 + i * 16 + rr, kc);
#pragma unroll
            for (int j = 0; j < 2; ++j)
                bl[j] = frag_bf16(Bs_lo + c * BN * 64, wn * 32 + j * 16 + rr, kc);

#pragma unroll
            for (int i = 0; i < 2; ++i)
#pragma unroll
                for (int j = 0; j < 2; ++j)
                    acc[i][j] = __builtin_amdgcn_mfma_f32_16x16x32_bf16(ah[i], bh[j], acc[i][j], 0, 0, 0);
#pragma unroll
            for (int i = 0; i < 2; ++i)
#pragma unroll
                for (int j = 0; j < 2; ++j)
                    acc[i][j] = __builtin_amdgcn_mfma_f32_16x16x32_bf16(ah[i], bl[j], acc[i][j], 0, 0, 0);
#pragma unroll
            for (int i = 0; i < 2; ++i)
#pragma unroll
                for (int j = 0; j < 2; ++j)
                    acc[i][j] = __builtin_amdgcn_mfma_f32_16x16x32_bf16(al[i], bh[j], acc[i][j], 0, 0, 0);
        }
        __syncthreads();
    }

    // fp32 partial epilogue into slice z
    const int lr = lane >> 4;
    const int lc = lane & 15;
    float* Cz = Cpart + (size_t)z * EMBED * EMBED;
#pragma unroll
    for (int i = 0; i < 2; ++i)
#pragma unroll
        for (int j = 0; j < 2; ++j)
#pragma unroll
            for (int r = 0; r < 4; ++r) {
                const int row = m0 + wm * 32 + i * 16 + lr * 4 + r;
                const int col = n0 + wn * 32 + j * 16 + lc;
                Cz[(size_t)row * EMBED + col] = acc[i][j][r];
            }
}

// ---------------------------------------------------------------------------
// Merge 4 fp32 T-partials -> split bf16 (Thi, Tlo). 1024 blocks x 256 thr.
// ---------------------------------------------------------------------------
__global__ __launch_bounds__(256) void t_merge(const float4* __restrict__ P,
                                               ushort4* __restrict__ Thi,
                                               ushort4* __restrict__ Tlo) {
    const int idx = blockIdx.x * 256 + threadIdx.x;   // over EMBED*EMBED/4
    const int S = EMBED * EMBED / 4;
    const float4 a = P[idx], b = P[idx + S], c = P[idx + 2 * S], d = P[idx + 3 * S];
    float4 s;
    s.x = (a.x + b.x) + (c.x + d.x);
    s.y = (a.y + b.y) + (c.y + d.y);
    s.z = (a.z + b.z) + (c.z + d.z);
    s.w = (a.w + b.w) + (c.w + d.w);
    ushort4 h, l;
    h.x = f2bf(s.x); l.x = f2bf(s.x - bf2f(h.x));
    h.y = f2bf(s.y); l.y = f2bf(s.y - bf2f(h.y));
    h.z = f2bf(s.z); l.z = f2bf(s.z - bf2f(h.z));
    h.w = f2bf(s.w); l.w = f2bf(s.w - bf2f(h.w));
    Thi[idx] = h; Tlo[idx] = l;
}

// ---------------------------------------------------------------------------
// Qf GEMM: Qf[4096,1024] = X[4096,1024] @ T^T, 3-pass split bf16.
// A operand: fp32 X, reg-staged with in-kernel hi/lo bf16 split, software-
// pipelined (loads for step s+1 issued before compute(s); convert+write
// after the barrier — T14 issue-early/write-late).
// B operand: Thi/Tlo via double-buffered global_load_lds issued before
// compute (T3 minimum 2-phase).
// 512 threads / 8 waves, per-wave 32x32 tile. LDS 64 KB -> 2 blocks/CU.
// XCD-aware bijective swizzle. Epilogue: fp32 Qf + i8 Qi8.
// ---------------------------------------------------------------------------
__global__ __launch_bounds__(512, 4) void qf_gemm(
        const float* __restrict__ X,
        const unsigned short* __restrict__ Bhi, const unsigned short* __restrict__ Blo,
        float* __restrict__ C, signed char* __restrict__ Ci8)
{
    constexpr int BM = 128, BN = 64, NCH = 2;             // K-step = 64
    __shared__ __align__(16) char As_hi[BM * 64 * NCH];   // 16 KB
    __shared__ __align__(16) char As_lo[BM * 64 * NCH];   // 16 KB
    __shared__ __align__(16) char Bs_hi[2][BN * 64 * NCH]; // 16 KB (dbuf)
    __shared__ __align__(16) char Bs_lo[2][BN * 64 * NCH]; // 16 KB (dbuf)

    const int t = threadIdx.x;
    const int lane = t & 63, wave = t >> 6;
    const int wm = wave >> 1, wn = wave & 1;              // 4x2 wave grid

    // XCD swizzle: 512 blocks = 8 XCD x 64; per XCD 4 m-panels x 16 n-tiles
    const int bid = blockIdx.y * 16 + blockIdx.x;
    const int g = bid & 7, ii = bid >> 3;                 // ii in 0..63
    const int m0 = (g * 4 + (ii >> 4)) * BM;
    const int n0 = (ii & 15) * BN;

    f32x4 acc[2][2];
#pragma unroll
    for (int i = 0; i < 2; ++i)
#pragma unroll
        for (int j = 0; j < 2; ++j)
#pragma unroll
            for (int r = 0; r < 4; ++r) acc[i][j][r] = 0.f;

    // A staging: thread -> one 16B bf16 chunk (8 elems) per 32-K sub-chunk
    const int arow = t >> 2, aslot = t & 3;
    const float* ag = X + (size_t)(m0 + arow) * EMBED + aslot * 8;
    char* ah_w = As_hi + arow * 64 + frag_slot(arow, aslot) * 16;
    char* al_w = As_lo + arow * 64 + frag_slot(arow, aslot) * 16;

    // B staging: waves 0-3 stage Bs_hi, waves 4-7 stage Bs_lo (16 rows each)
    const unsigned short* bsrc = (wave < 4) ? Bhi : Blo;
    const int w4 = wave & 3;
    const int brow0 = w4 * 16;
    const int b_rloc = lane >> 2;
    const int b_kc = (lane - (lane >> 3)) & 3;
    const char* bg = (const char*)(bsrc + (size_t)(n0 + brow0 + b_rloc) * EMBED) + b_kc * 16;
    char* bdst0 = ((wave < 4) ? Bs_hi[0] : Bs_lo[0]) + brow0 * 64;  // wave-uniform
    char* bdst1 = ((wave < 4) ? Bs_hi[1] : Bs_lo[1]) + brow0 * 64;

    const int kc = lane >> 4;
    const int rr = lane & 15;

    // ---- prologue: step 0 ----
    {
        float4 f0[NCH][2];
#pragma unroll
        for (int c = 0; c < NCH; ++c) {
            f0[c][0] = *(const float4*)(ag + c * 32);
            f0[c][1] = *(const float4*)(ag + c * 32 + 4);
            async16(bg + (size_t)(c * 32) * 2, bdst0 + c * BN * 64);
        }
#pragma unroll
        for (int c = 0; c < NCH; ++c)
            cvt8_write(f0[c][0], f0[c][1], ah_w + c * BM * 64, al_w + c * BM * 64);
    }
    __syncthreads();

    for (int s = 0; s < 16; ++s) {
        const int cur = s & 1;
        char* bnxt = cur ? bdst0 : bdst1;
        float4 fn[NCH][2];
        if (s < 15) {
            const int kn = (s + 1) * 64;
#pragma unroll
            for (int c = 0; c < NCH; ++c) {
                fn[c][0] = *(const float4*)(ag + kn + c * 32);
                fn[c][1] = *(const float4*)(ag + kn + c * 32 + 4);
                async16(bg + (size_t)(kn + c * 32) * 2, bnxt + c * BN * 64);
            }
        }

        // compute step s
        const char* bh_l = Bs_hi[cur];
        const char* bl_l = Bs_lo[cur];
#pragma unroll
        for (int c = 0; c < NCH; ++c) {
            s16x8 ah[2], bh[2], al[2], bl[2];
#pragma unroll
            for (int i = 0; i < 2; ++i)
                ah[i] = frag_bf16(As_hi + c * BM * 64, wm * 32 + i * 16 + rr, kc);
#pragma unroll
            for (int j = 0; j < 2; ++j)
                bh[j] = frag_bf16(bh_l + c * BN * 64, wn * 32 + j * 16 + rr, kc);
#pragma unroll
            for (int i = 0; i < 2; ++i)
                al[i] = frag_bf16(As_lo + c * BM * 64, wm * 32 + i * 16 + rr, kc);
#pragma unroll
            for (int j = 0; j < 2; ++j)
                bl[j] = frag_bf16(bl_l + c * BN * 64, wn * 32 + j * 16 + rr, kc);

#pragma unroll
            for (int i = 0; i < 2; ++i)
#pragma unroll
                for (int j = 0; j < 2; ++j)
                    acc[i][j] = __builtin_amdgcn_mfma_f32_16x16x32_bf16(ah[i], bh[j], acc[i][j], 0, 0, 0);
#pragma unroll
            for (int i = 0; i < 2; ++i)
#pragma unroll
                for (int j = 0; j < 2; ++j)
                    acc[i][j] = __builtin_amdgcn_mfma_f32_16x16x32_bf16(ah[i], bl[j], acc[i][j], 0, 0, 0);
#pragma unroll
            for (int i = 0; i < 2; ++i)
#pragma unroll
                for (int j = 0; j < 2; ++j)
                    acc[i][j] = __builtin_amdgcn_mfma_f32_16x16x32_bf16(al[i], bh[j], acc[i][j], 0, 0, 0);
        }
        __syncthreads();   // As readers done; vmcnt drained (fn + B-next landed under compute)
        if (s < 15) {
#pragma unroll
            for (int c = 0; c < NCH; ++c)
                cvt8_write(fn[c][0], fn[c][1], ah_w + c * BM * 64, al_w + c * BM * 64);
        }
        __syncthreads();   // publish As for step s+1
    }

    // Epilogue: C/D layout col=lane&15, row=(lane>>4)*4+reg
    const int lr = lane >> 4;
    const int lc = lane & 15;
#pragma unroll
    for (int i = 0; i < 2; ++i)
#pragma unroll
        for (int j = 0; j < 2; ++j)
#pragma unroll
            for (int r = 0; r < 4; ++r) {
                const int row = m0 + wm * 32 + i * 16 + lr * 4 + r;
                const int col = n0 + wn * 32 + j * 16 + lc;
                const float v = acc[i][j][r];
                const size_t idx = (size_t)row * EMBED + col;
                C[idx] = v;
                const float q = fminf(fmaxf(v * SQ_INV, -127.f), 127.f);
                Ci8[idx] = (signed char)(int)rintf(q);
            }
}

// ---------------------------------------------------------------------------
// i8 scores GEMM + write-only candidate selection. 2-phase double-buffered:
// K-step 64, stage(t+1) issued BEFORE compute(t), one barrier per step.
// LDS unchanged at 32 KB (occupancy preserved). Tile 128x128, grid (32,32),
// XCD swizzle: each XCD owns 4 m-panels x all n.
// ---------------------------------------------------------------------------
__global__ __launch_bounds__(256) void gemm_i8_scores(
        const signed char* __restrict__ A,   // Qi8 [NTOK, EMBED]
        const signed char* __restrict__ B,   // Xi8 [NTOK, EMBED]
        float* __restrict__ tmax, int* __restrict__ cnts, int2* __restrict__ cand)
{
    __shared__ __align__(16) char As[2][128 * 64];
    __shared__ __align__(16) char Bs[2][128 * 64];

    const int t = threadIdx.x;
    const int lane = t & 63, wave = t >> 6;
    const int wm = wave >> 1, wn = wave & 1;

    // XCD swizzle: 1024 blocks = 8 XCD x 128; per XCD 4 m-panels x 32 n-tiles
    const int bid = blockIdx.y * 32 + blockIdx.x;
    const int g = bid & 7, ii = bid >> 3;                 // ii in 0..127
    const int by = g * 4 + (ii >> 5);
    const int bx = ii & 31;
    const int m0 = by * 128, n0 = bx * 128;

    i32x4 acc[4][4];
#pragma unroll
    for (int i = 0; i < 4; ++i)
#pragma unroll
        for (int j = 0; j < 4; ++j)
#pragma unroll
            for (int r = 0; r < 4; ++r) acc[i][j][r] = 0;

    const char* a_g = (const char*)A + (size_t)m0 * EMBED;
    const char* b_g = (const char*)B + (size_t)n0 * EMBED;
    const int kc = lane >> 4;
    const int rr = lane & 15;

    // prologue: stage step 0
    stage_rows<128>(a_g, EMBED, As[0], wave, lane);
    stage_rows<128>(b_g, EMBED, Bs[0], wave, lane);
    __syncthreads();

    for (int s = 0; s < 16; ++s) {
        const int cur = s & 1;
        if (s < 15) {
            stage_rows<128>(a_g + (s + 1) * 64, EMBED, As[cur ^ 1], wave, lane);
            stage_rows<128>(b_g + (s + 1) * 64, EMBED, Bs[cur ^ 1], wave, lane);
        }
        i32x4 af[4], bf[4];
#pragma unroll
        for (int i = 0; i < 4; ++i) af[i] = frag_i8(As[cur], wm * 64 + i * 16 + rr, kc);
#pragma unroll
        for (int j = 0; j < 4; ++j) bf[j] = frag_i8(Bs[cur], wn * 64 + j * 16 + rr, kc);
#pragma unroll
        for (int i = 0; i < 4; ++i)
#pragma unroll
            for (int j = 0; j < 4; ++j)
                acc[i][j] = __builtin_amdgcn_mfma_i32_16x16x64_i8(af[i], bf[j], acc[i][j], 0, 0, 0);
        __syncthreads();   // readers of buf[cur] done; stage(t+1) drained (landed under compute)
    }

    // Write-only local selection epilogue.
    const int lr = lane >> 4;
    const int lc = lane & 15;
    const int wslot = bx * 2 + wn;                        // 64 slots per row
    const unsigned long long grp = 0xFFFFull << (lr * 16);
    const unsigned long long low = (lane == 63) ? 0x7FFFFFFFFFFFFFFFull
                                                : ((1ull << lane) - 1);
#pragma unroll
    for (int i = 0; i < 4; ++i)
#pragma unroll
        for (int r = 0; r < 4; ++r) {
            const int row = m0 + wm * 64 + i * 16 + lr * 4 + r;
            float v[4];
            float vmax = -3.4e38f;
#pragma unroll
            for (int j = 0; j < 4; ++j) {
                v[j] = (float)acc[i][j][r] * SCLOGIT;
                vmax = fmaxf(vmax, v[j]);
            }
#pragma unroll
            for (int msk = 1; msk < 16; msk <<= 1)
                vmax = fmaxf(vmax, __shfl_xor(vmax, msk, 64));
            const float thr = vmax - MARGIN;
            int base = 0;
#pragma unroll
            for (int j = 0; j < 4; ++j) {
                const bool pred = v[j] > thr;
                const unsigned long long m = __ballot(pred) & grp;
                if (pred) {
                    const int pos = base + __popcll(m & low);
                    if (pos < KC)
                        cand[((size_t)row * 64 + wslot) * KC + pos] =
                            make_int2(n0 + wn * 64 + j * 16 + lc,
                                      __float_as_int(v[j]));
                }
                base += __popcll(m);
            }
            if (lc == 0) {
                tmax[(size_t)row * 64 + wslot] = vmax;
                cnts[(size_t)row * 64 + wslot] = base < KC ? base : KC;
            }
        }
}

// ---------------------------------------------------------------------------
// Final: global row max over 64 tile maxima, filter stored candidates,
// wave-parallel exact fp32 logits, softmax, blend fp32 X rows. 1 block/row.
// ---------------------------------------------------------------------------
__global__ __launch_bounds__(256) void sparse_out(const float* __restrict__ tmax,
                                                  const int* __restrict__ cnts,
                                                  const int2* __restrict__ cand,
                                                  const float* __restrict__ Qf,
                                                  const float* __restrict__ X,
                                                  float* __restrict__ out) {
    const int t = threadIdx.x;
    const int lane = t & 63, wave = t >> 6;
    const int row = blockIdx.x;

    __shared__ float gmax_s;
    __shared__ int   n2;
    __shared__ int   list[CAP];
    __shared__ float ll[CAP];
    if (t == 0) n2 = 0;

    // global row max over 64 tile maxima (wave 0)
    float gm = -3.4e38f;
    if (t < 64) gm = tmax[(size_t)row * 64 + t];
#pragma unroll
    for (int off = 32; off >= 1; off >>= 1) gm = fmaxf(gm, __shfl_xor(gm, off, 64));
    if (t == 0) gmax_s = gm;
    __syncthreads();
    const float thr = gmax_s - MARGIN;

    // filter stored candidates (64 slots x KC entries)
    for (int e = t; e < 64 * KC; e += 256) {
        const int s = e >> 3, k = e & (KC - 1);
        if (k < cnts[(size_t)row * 64 + s]) {
            const int2 c = cand[((size_t)row * 64 + s) * KC + k];
            if (__int_as_float(c.y) > thr) {
                const int p = atomicAdd(&n2, 1);   // LDS atomic
                if (p < CAP) list[p] = c.x;
            }
        }
    }
    __syncthreads();
    const int nc = min(n2, CAP);

    // exact logits, wave-parallel: candidate c handled by wave (c & 3)
    float4 q[4];
#pragma unroll
    for (int i = 0; i < 4; ++i)
        q[i] = *(const float4*)&Qf[(size_t)row * EMBED + lane * 16 + i * 4];
    for (int c = wave; c < nc; c += 4) {
        const float* xp = &X[(size_t)list[c] * EMBED + lane * 16];
        float p = 0.f;
#pragma unroll
        for (int i = 0; i < 4; ++i) {
            const float4 x4 = *(const float4*)(xp + i * 4);
            p += q[i].x * x4.x + q[i].y * x4.y + q[i].z * x4.z + q[i].w * x4.w;
        }
#pragma unroll
        for (int off = 32; off >= 1; off >>= 1) p += __shfl_xor(p, off, 64);
        if (lane == 0) ll[c] = p * 0.03125f;
    }
    __syncthreads();

    // exact softmax over candidates (redundant per thread; nc is tiny)
    float mt = -3.4e38f;
    for (int c = 0; c < nc; ++c) mt = fmaxf(mt, ll[c]);
    float wsum = 0.f;
    for (int c = 0; c < nc; ++c) wsum += __expf(ll[c] - mt);
    const float inv = 1.0f / wsum;

    float4 o = {0.f, 0.f, 0.f, 0.f};
    for (int c = 0; c < nc; ++c) {
        const float w = __expf(ll[c] - mt);
        const float4 xj = *(const float4*)&X[(size_t)list[c] * EMBED + t * 4];
        o.x += w * xj.x; o.y += w * xj.y; o.z += w * xj.z; o.w += w * xj.w;
    }
    o.x *= inv; o.y *= inv; o.z *= inv; o.w *= inv;
    *(float4*)&out[(size_t)row * EMBED + t * 4] = o;
}

extern "C" void kernel_launch(void* const* d_in, const int* in_sizes, int n_in,
                              void* d_out, int out_size, void* d_ws, size_t ws_size,
                              hipStream_t stream) {
    const float* X  = (const float*)d_in[0];  // [4096,1024]
    const float* Wq = (const float*)d_in[1];  // [1024,1024]
    const float* Wk = (const float*)d_in[2];  // [1024,1024]
    float* out = (float*)d_out;

    char* ws = (char*)d_ws;
    const size_t MB = 1024 * 1024;
    signed char*    Xi8 = (signed char*)(ws + 16 * MB);     // 4 MB
    float*          Qf  = (float*)(ws + 20 * MB);           // 16 MB
    signed char*    Qi8 = (signed char*)(ws + 36 * MB);     // 4 MB
    float* tmax = (float*)(ws + 40 * MB);                   // 1 MB
    int*   cnts = (int*)(ws + 41 * MB);                     // 1 MB
    int2*  cand = (int2*)(ws + 42 * MB);                    // 16 MB
    unsigned short* Wqhi = (unsigned short*)(ws + 58 * MB);
    unsigned short* Wqlo = (unsigned short*)(ws + 60 * MB);
    unsigned short* Wkhi = (unsigned short*)(ws + 62 * MB);
    unsigned short* Wklo = (unsigned short*)(ws + 64 * MB);
    unsigned short* Thi  = (unsigned short*)(ws + 66 * MB);
    unsigned short* Tlo  = (unsigned short*)(ws + 68 * MB);
    // T fp32 partials (4 x 4 MB) alias the cand region: written/consumed
    // (t_gemm -> t_merge) strictly before gemm_i8_scores writes cand.
    float* Tpart = (float*)(ws + 42 * MB);                  // 16 MB

    // 1) prep: W hi/lo splits + X -> i8
    prep<<<6144, 256, 0, stream>>>(
        (const float4*)X, (const float4*)Wq, (const float4*)Wk, (char4*)Xi8,
        (ushort4*)Wqhi, (ushort4*)Wqlo, (ushort4*)Wkhi, (ushort4*)Wklo);

    // 2) split-K=4 T-partials (T = Wk @ Wq^T = M^T)
    t_gemm<<<dim3(16, 16, 4), 256, 0, stream>>>(
        Wkhi, Wklo, Wqhi, Wqlo, Tpart);

    // 3) merge partials -> split bf16 T
    t_merge<<<1024, 256, 0, stream>>>((const float4*)Tpart,
                                      (ushort4*)Thi, (ushort4*)Tlo);

    // 4) Qf = X @ T^T (= X @ M): pipelined fp32-A split, dbuf B, XCD swizzle
    qf_gemm<<<dim3(16, 32), 512, 0, stream>>>(
        X, Thi, Tlo, Qf, Qi8);

    // 5) i8 cheap scores (2-phase dbuf, K-step 64) + candidate selection
    gemm_i8_scores<<<dim3(32, 32), 256, 0, stream>>>(Qi8, Xi8, tmax, cnts, cand);

    // 6) exact sparse softmax + gather
    sparse_out<<<NTOK, 256, 0, stream>>>(tmax, cnts, cand, Qf, X, out);
}

// Round 4
// 178.560 us; speedup vs baseline: 1.0139x; 1.0139x over previous
//
#include <hip/hip_runtime.h>

#define EMBED 1024
#define NTOK  4096
#define MARGIN 256.0f   // i8 cheap-logit error sigma ~22; 2*5.5sigma + window
#define KC     8        // candidate slots per (row, wave-tile)
#define CAP    128      // final per-row candidate cap

// i8 scales: Xi8 = round(X * 127/5), Qi8 = round(Q' * 127/8192)
#define SX_INV 25.4f
#define SQ_INV 0.0155029296875f
#define SCLOGIT 0.07936198f   // (8192/127)*(5/127)/32

typedef short  s16x8 __attribute__((ext_vector_type(8)));
typedef float  f32x4 __attribute__((ext_vector_type(4)));
typedef int    i32x4 __attribute__((ext_vector_type(4)));

// ---- bf16 helpers (RNE) ----------------------------------------------------
__device__ __forceinline__ unsigned short f2bf(float f) {
    unsigned int u = __float_as_uint(f);
    u = (u + 0x7FFFu + ((u >> 16) & 1u)) >> 16;
    return (unsigned short)u;
}
__device__ __forceinline__ float bf2f(unsigned short h) {
    return __uint_as_float(((unsigned int)h) << 16);
}

// ---- async 16B global->LDS -------------------------------------------------
__device__ __forceinline__ void async16(const void* g, void* l) {
    __builtin_amdgcn_global_load_lds(
        (const __attribute__((address_space(1))) unsigned int*)g,
        (__attribute__((address_space(3))) unsigned int*)l, 16, 0, 0);
}

// Stage ROWS x 64-byte rows (row-major, swizzled 16B chunks) into LDS.
// ld in BYTES. 4-wave (256-thread) version.
template<int ROWS>
__device__ __forceinline__ void stage_rows(const char* __restrict__ g,
                                           int ld, char* lds, int wave, int lane) {
#pragma unroll
    for (int r = 0; r < ROWS / 64; ++r) {
        const int row0 = (wave * (ROWS / 64) + r) * 16;   // wave-uniform
        const int r_loc = lane >> 2;
        const int kc = (lane - (lane >> 3)) & 3;          // (slot - r_loc/2) & 3
        const char* gp = g + (size_t)(row0 + r_loc) * ld + kc * 16;
        char* lp = lds + row0 * 64;                       // wave-uniform base
        async16(gp, lp);
    }
}

// 8-wave (512-thread) version. ROWS must be a multiple of 128.
template<int ROWS>
__device__ __forceinline__ void stage_rows8(const char* __restrict__ g,
                                            int ld, char* lds, int wave, int lane) {
#pragma unroll
    for (int r = 0; r < ROWS / 128; ++r) {
        const int row0 = (wave * (ROWS / 128) + r) * 16;  // wave-uniform
        const int r_loc = lane >> 2;
        const int kc = (lane - (lane >> 3)) & 3;
        const char* gp = g + (size_t)(row0 + r_loc) * ld + kc * 16;
        char* lp = lds + row0 * 64;                       // wave-uniform base
        async16(gp, lp);
    }
}

__device__ __forceinline__ int frag_slot(int row, int kc) {
    return (kc + ((row & 15) >> 1)) & 3;
}
__device__ __forceinline__ s16x8 frag_bf16(const char* lds, int row, int kc) {
    return *(const s16x8*)(lds + row * 64 + frag_slot(row, kc) * 16);
}
__device__ __forceinline__ i32x4 frag_i8(const char* lds, int row, int kc) {
    return *(const i32x4*)(lds + row * 64 + frag_slot(row, kc) * 16);
}

// convert 8 fp32 -> bf16 hi/lo and store 16B each to LDS
__device__ __forceinline__ void cvt8_write(float4 a, float4 b, char* hw, char* lw) {
    float fs[8] = {a.x, a.y, a.z, a.w, b.x, b.y, b.z, b.w};
    s16x8 hv, lv;
#pragma unroll
    for (int e = 0; e < 8; ++e) {
        const unsigned short h = f2bf(fs[e]);
        hv[e] = (short)h;
        lv[e] = (short)f2bf(fs[e] - bf2f(h));
    }
    *(s16x8*)hw = hv;
    *(s16x8*)lw = lv;
}

// ---------------------------------------------------------------------------
// prep: W -> bf16 hi/lo splits, X -> i8 only. 6144 blocks x 256 threads.
// ---------------------------------------------------------------------------
__global__ __launch_bounds__(256) void prep(
        const float4* __restrict__ X, const float4* __restrict__ Wq,
        const float4* __restrict__ Wk, char4* __restrict__ Xi8,
        ushort4* __restrict__ Wqhi, ushort4* __restrict__ Wqlo,
        ushort4* __restrict__ Wkhi, ushort4* __restrict__ Wklo) {
    const int NW4 = EMBED * EMBED / 4;                    // 262144
    const int n = blockIdx.x * 256 + threadIdx.x;
    if (n < 2 * NW4) {
        const float4* src;
        ushort4 *hi, *lo;
        int idx;
        if (n < NW4) { src = Wq; hi = Wqhi; lo = Wqlo; idx = n; }
        else         { src = Wk; hi = Wkhi; lo = Wklo; idx = n - NW4; }
        const float4 v = src[idx];
        ushort4 h, l;
        h.x = f2bf(v.x); l.x = f2bf(v.x - bf2f(h.x));
        h.y = f2bf(v.y); l.y = f2bf(v.y - bf2f(h.y));
        h.z = f2bf(v.z); l.z = f2bf(v.z - bf2f(h.z));
        h.w = f2bf(v.w); l.w = f2bf(v.w - bf2f(h.w));
        hi[idx] = h; lo[idx] = l;
    } else {
        const int idx = n - 2 * NW4;                      // over NTOK*EMBED/4
        const float4 v = X[idx];
        char4 c;
        c.x = (signed char)(int)rintf(fminf(fmaxf(v.x * SX_INV, -127.f), 127.f));
        c.y = (signed char)(int)rintf(fminf(fmaxf(v.y * SX_INV, -127.f), 127.f));
        c.z = (signed char)(int)rintf(fminf(fmaxf(v.z * SX_INV, -127.f), 127.f));
        c.w = (signed char)(int)rintf(fminf(fmaxf(v.w * SX_INV, -127.f), 127.f));
        Xi8[idx] = c;
    }
}

// ---------------------------------------------------------------------------
// Split-K=4 T-partial GEMM. T = Wk @ Wq^T, 3-pass split bf16, 64x64 tile,
// K-slice = 256 per z. Partials to Cpart[z] (fp32, no atomics).
// grid (16,16,4), 256 threads.
// ---------------------------------------------------------------------------
__global__ __launch_bounds__(256) void t_gemm(
        const unsigned short* __restrict__ Ahi, const unsigned short* __restrict__ Alo,
        const unsigned short* __restrict__ Bhi, const unsigned short* __restrict__ Blo,
        float* __restrict__ Cpart)
{
    constexpr int BM = 64, BN = 64, NCH = 2;
    __shared__ __align__(16) char As_hi[BM * 64 * NCH];
    __shared__ __align__(16) char Bs_hi[BN * 64 * NCH];
    __shared__ __align__(16) char As_lo[BM * 64 * NCH];
    __shared__ __align__(16) char Bs_lo[BN * 64 * NCH];

    const int t = threadIdx.x;
    const int z = blockIdx.z;
    const int lane = t & 63, wave = t >> 6;
    const int wm = wave >> 1, wn = wave & 1;
    const int m0 = blockIdx.y * BM, n0 = blockIdx.x * BN;

    f32x4 acc[2][2];
#pragma unroll
    for (int i = 0; i < 2; ++i)
#pragma unroll
        for (int j = 0; j < 2; ++j)
#pragma unroll
            for (int r = 0; r < 4; ++r) acc[i][j][r] = 0.f;

    const char* ah_g = (const char*)(Ahi + (size_t)m0 * EMBED);
    const char* bh_g = (const char*)(Bhi + (size_t)n0 * EMBED);
    const char* al_g = (const char*)(Alo + (size_t)m0 * EMBED);
    const char* bl_g = (const char*)(Blo + (size_t)n0 * EMBED);

    const int kc = lane >> 4;
    const int rr = lane & 15;
    const int kbeg = z * 256;

    for (int k0 = kbeg; k0 < kbeg + 256; k0 += 32 * NCH) {
#pragma unroll
        for (int c = 0; c < NCH; ++c) {
            const int kb = (k0 + 32 * c) * 2;
            stage_rows<BM>(ah_g + kb, EMBED * 2, As_hi + c * BM * 64, wave, lane);
            stage_rows<BN>(bh_g + kb, EMBED * 2, Bs_hi + c * BN * 64, wave, lane);
            stage_rows<BM>(al_g + kb, EMBED * 2, As_lo + c * BM * 64, wave, lane);
            stage_rows<BN>(bl_g + kb, EMBED * 2, Bs_lo + c * BN * 64, wave, lane);
        }
        __syncthreads();

#pragma unroll
        for (int c = 0; c < NCH; ++c) {
            s16x8 ah[2], bh[2], al[2], bl[2];
#pragma unroll
            for (int i = 0; i < 2; ++i)
                ah[i] = frag_bf16(As_hi + c * BM * 64, wm * 32 + i * 16 + rr, kc);
#pragma unroll
            for (int j = 0; j < 2; ++j)
                bh[j] = frag_bf16(Bs_hi + c * BN * 64, wn * 32 + j * 16 + rr, kc);
#pragma unroll
            for (int i = 0; i < 2; ++i)
                al[i] = frag_bf16(As_lo + c * BM * 64, wm * 32 + i * 16 + rr, kc);
#pragma unroll
            for (int j = 0; j < 2; ++j)
                bl[j] = frag_bf16(Bs_lo + c * BN * 64, wn * 32 + j * 16 + rr, kc);

#pragma unroll
            for (int i = 0; i < 2; ++i)
#pragma unroll
                for (int j = 0; j < 2; ++j)
                    acc[i][j] = __builtin_amdgcn_mfma_f32_16x16x32_bf16(ah[i], bh[j], acc[i][j], 0, 0, 0);
#pragma unroll
            for (int i = 0; i < 2; ++i)
#pragma unroll
                for (int j = 0; j < 2; ++j)
                    acc[i][j] = __builtin_amdgcn_mfma_f32_16x16x32_bf16(ah[i], bl[j], acc[i][j], 0, 0, 0);
#pragma unroll
            for (int i = 0; i < 2; ++i)
#pragma unroll
                for (int j = 0; j < 2; ++j)
                    acc[i][j] = __builtin_amdgcn_mfma_f32_16x16x32_bf16(al[i], bh[j], acc[i][j], 0, 0, 0);
        }
        __syncthreads();
    }

    // fp32 partial epilogue into slice z
    const int lr = lane >> 4;
    const int lc = lane & 15;
    float* Cz = Cpart + (size_t)z * EMBED * EMBED;
#pragma unroll
    for (int i = 0; i < 2; ++i)
#pragma unroll
        for (int j = 0; j < 2; ++j)
#pragma unroll
            for (int r = 0; r < 4; ++r) {
                const int row = m0 + wm * 32 + i * 16 + lr * 4 + r;
                const int col = n0 + wn * 32 + j * 16 + lc;
                Cz[(size_t)row * EMBED + col] = acc[i][j][r];
            }
}

// ---------------------------------------------------------------------------
// Merge 4 fp32 T-partials -> split bf16 (Thi, Tlo). 1024 blocks x 256 thr.
// ---------------------------------------------------------------------------
__global__ __launch_bounds__(256) void t_merge(const float4* __restrict__ P,
                                               ushort4* __restrict__ Thi,
                                               ushort4* __restrict__ Tlo) {
    const int idx = blockIdx.x * 256 + threadIdx.x;   // over EMBED*EMBED/4
    const int S = EMBED * EMBED / 4;
    const float4 a = P[idx], b = P[idx + S], c = P[idx + 2 * S], d = P[idx + 3 * S];
    float4 s;
    s.x = (a.x + b.x) + (c.x + d.x);
    s.y = (a.y + b.y) + (c.y + d.y);
    s.z = (a.z + b.z) + (c.z + d.z);
    s.w = (a.w + b.w) + (c.w + d.w);
    ushort4 h, l;
    h.x = f2bf(s.x); l.x = f2bf(s.x - bf2f(h.x));
    h.y = f2bf(s.y); l.y = f2bf(s.y - bf2f(h.y));
    h.z = f2bf(s.z); l.z = f2bf(s.z - bf2f(h.z));
    h.w = f2bf(s.w); l.w = f2bf(s.w - bf2f(h.w));
    Thi[idx] = h; Tlo[idx] = l;
}

// ---------------------------------------------------------------------------
// Qf GEMM: Qf[4096,1024] = X[4096,1024] @ T^T, 3-pass split bf16.
// A operand: fp32 X, reg-staged with in-kernel hi/lo bf16 split, software-
// pipelined (loads for step s+1 issued before compute(s); convert+write
// after the barrier). B operand: Thi/Tlo via double-buffered global_load_lds
// issued before compute. 512 threads / 8 waves, per-wave 32x32 tile.
// LDS 64 KB -> 2 blocks/CU. XCD swizzle. Epilogue: fp32 Qf + i8 Qi8.
// (Kept from R3: barrier count per K unchanged vs serial; A-prefetch lands
// in registers so it is not behind the vmcnt drain.)
// ---------------------------------------------------------------------------
__global__ __launch_bounds__(512, 4) void qf_gemm(
        const float* __restrict__ X,
        const unsigned short* __restrict__ Bhi, const unsigned short* __restrict__ Blo,
        float* __restrict__ C, signed char* __restrict__ Ci8)
{
    constexpr int BM = 128, BN = 64, NCH = 2;             // K-step = 64
    __shared__ __align__(16) char As_hi[BM * 64 * NCH];   // 16 KB
    __shared__ __align__(16) char As_lo[BM * 64 * NCH];   // 16 KB
    __shared__ __align__(16) char Bs_hi[2][BN * 64 * NCH]; // 16 KB (dbuf)
    __shared__ __align__(16) char Bs_lo[2][BN * 64 * NCH]; // 16 KB (dbuf)

    const int t = threadIdx.x;
    const int lane = t & 63, wave = t >> 6;
    const int wm = wave >> 1, wn = wave & 1;              // 4x2 wave grid

    // XCD swizzle: 512 blocks = 8 XCD x 64; per XCD 4 m-panels x 16 n-tiles
    const int bid = blockIdx.y * 16 + blockIdx.x;
    const int g = bid & 7, ii = bid >> 3;                 // ii in 0..63
    const int m0 = (g * 4 + (ii >> 4)) * BM;
    const int n0 = (ii & 15) * BN;

    f32x4 acc[2][2];
#pragma unroll
    for (int i = 0; i < 2; ++i)
#pragma unroll
        for (int j = 0; j < 2; ++j)
#pragma unroll
            for (int r = 0; r < 4; ++r) acc[i][j][r] = 0.f;

    // A staging: thread -> one 16B bf16 chunk (8 elems) per 32-K sub-chunk
    const int arow = t >> 2, aslot = t & 3;
    const float* ag = X + (size_t)(m0 + arow) * EMBED + aslot * 8;
    char* ah_w = As_hi + arow * 64 + frag_slot(arow, aslot) * 16;
    char* al_w = As_lo + arow * 64 + frag_slot(arow, aslot) * 16;

    // B staging: waves 0-3 stage Bs_hi, waves 4-7 stage Bs_lo (16 rows each)
    const unsigned short* bsrc = (wave < 4) ? Bhi : Blo;
    const int w4 = wave & 3;
    const int brow0 = w4 * 16;
    const int b_rloc = lane >> 2;
    const int b_kc = (lane - (lane >> 3)) & 3;
    const char* bg = (const char*)(bsrc + (size_t)(n0 + brow0 + b_rloc) * EMBED) + b_kc * 16;
    char* bdst0 = ((wave < 4) ? Bs_hi[0] : Bs_lo[0]) + brow0 * 64;  // wave-uniform
    char* bdst1 = ((wave < 4) ? Bs_hi[1] : Bs_lo[1]) + brow0 * 64;

    const int kc = lane >> 4;
    const int rr = lane & 15;

    // ---- prologue: step 0 ----
    {
        float4 f0[NCH][2];
#pragma unroll
        for (int c = 0; c < NCH; ++c) {
            f0[c][0] = *(const float4*)(ag + c * 32);
            f0[c][1] = *(const float4*)(ag + c * 32 + 4);
            async16(bg + (size_t)(c * 32) * 2, bdst0 + c * BN * 64);
        }
#pragma unroll
        for (int c = 0; c < NCH; ++c)
            cvt8_write(f0[c][0], f0[c][1], ah_w + c * BM * 64, al_w + c * BM * 64);
    }
    __syncthreads();

    for (int s = 0; s < 16; ++s) {
        const int cur = s & 1;
        char* bnxt = cur ? bdst0 : bdst1;
        float4 fn[NCH][2];
        if (s < 15) {
            const int kn = (s + 1) * 64;
#pragma unroll
            for (int c = 0; c < NCH; ++c) {
                fn[c][0] = *(const float4*)(ag + kn + c * 32);
                fn[c][1] = *(const float4*)(ag + kn + c * 32 + 4);
                async16(bg + (size_t)(kn + c * 32) * 2, bnxt + c * BN * 64);
            }
        }

        // compute step s
        const char* bh_l = Bs_hi[cur];
        const char* bl_l = Bs_lo[cur];
#pragma unroll
        for (int c = 0; c < NCH; ++c) {
            s16x8 ah[2], bh[2], al[2], bl[2];
#pragma unroll
            for (int i = 0; i < 2; ++i)
                ah[i] = frag_bf16(As_hi + c * BM * 64, wm * 32 + i * 16 + rr, kc);
#pragma unroll
            for (int j = 0; j < 2; ++j)
                bh[j] = frag_bf16(bh_l + c * BN * 64, wn * 32 + j * 16 + rr, kc);
#pragma unroll
            for (int i = 0; i < 2; ++i)
                al[i] = frag_bf16(As_lo + c * BM * 64, wm * 32 + i * 16 + rr, kc);
#pragma unroll
            for (int j = 0; j < 2; ++j)
                bl[j] = frag_bf16(bl_l + c * BN * 64, wn * 32 + j * 16 + rr, kc);

#pragma unroll
            for (int i = 0; i < 2; ++i)
#pragma unroll
                for (int j = 0; j < 2; ++j)
                    acc[i][j] = __builtin_amdgcn_mfma_f32_16x16x32_bf16(ah[i], bh[j], acc[i][j], 0, 0, 0);
#pragma unroll
            for (int i = 0; i < 2; ++i)
#pragma unroll
                for (int j = 0; j < 2; ++j)
                    acc[i][j] = __builtin_amdgcn_mfma_f32_16x16x32_bf16(ah[i], bl[j], acc[i][j], 0, 0, 0);
#pragma unroll
            for (int i = 0; i < 2; ++i)
#pragma unroll
                for (int j = 0; j < 2; ++j)
                    acc[i][j] = __builtin_amdgcn_mfma_f32_16x16x32_bf16(al[i], bh[j], acc[i][j], 0, 0, 0);
        }
        __syncthreads();   // As readers done; vmcnt drained (fn + B-next landed under compute)
        if (s < 15) {
#pragma unroll
            for (int c = 0; c < NCH; ++c)
                cvt8_write(fn[c][0], fn[c][1], ah_w + c * BM * 64, al_w + c * BM * 64);
        }
        __syncthreads();   // publish As for step s+1
    }

    // Epilogue: C/D layout col=lane&15, row=(lane>>4)*4+reg
    const int lr = lane >> 4;
    const int lc = lane & 15;
#pragma unroll
    for (int i = 0; i < 2; ++i)
#pragma unroll
        for (int j = 0; j < 2; ++j)
#pragma unroll
            for (int r = 0; r < 4; ++r) {
                const int row = m0 + wm * 32 + i * 16 + lr * 4 + r;
                const int col = n0 + wn * 32 + j * 16 + lc;
                const float v = acc[i][j][r];
                const size_t idx = (size_t)row * EMBED + col;
                C[idx] = v;
                const float q = fminf(fmaxf(v * SQ_INV, -127.f), 127.f);
                Ci8[idx] = (signed char)(int)rintf(q);
            }
}

// ---------------------------------------------------------------------------
// i8 scores GEMM + write-only candidate selection.
// REVERTED to m97-style 2-barrier loop (K-step 128, stage -> barrier ->
// compute -> barrier) after the 2-phase dbuf regressed (R3: 66us, the
// drain-to-0 barrier doubled exposed-latency windows).
// UPGRADED tile: 256x128, 512 threads / 8 waves, LDS 48 KB -> 2 blocks/CU,
// 512 blocks fully co-resident (zero tail). Per-wave 64x64 sub-tile and the
// selection epilogue are unchanged. XCD swizzle: 8 XCD x (2 m-panels x 32 n).
// ---------------------------------------------------------------------------
__global__ __launch_bounds__(512, 4) void gemm_i8_scores(
        const signed char* __restrict__ A,   // Qi8 [NTOK, EMBED]
        const signed char* __restrict__ B,   // Xi8 [NTOK, EMBED]
        float* __restrict__ tmax, int* __restrict__ cnts, int2* __restrict__ cand)
{
    __shared__ __align__(16) char As[256 * 64 * 2];   // 32 KB
    __shared__ __align__(16) char Bs[128 * 64 * 2];   // 16 KB

    const int t = threadIdx.x;
    const int lane = t & 63, wave = t >> 6;
    const int wm = wave >> 1, wn = wave & 1;          // 4x2 wave grid

    // XCD swizzle: 512 blocks = 8 XCD x 64; per XCD 2 m-panels x 32 n-tiles
    const int bid = blockIdx.y * 32 + blockIdx.x;
    const int g = bid & 7, ii = bid >> 3;             // ii in 0..63
    const int by = g * 2 + (ii >> 5);
    const int bx = ii & 31;
    const int m0 = by * 256, n0 = bx * 128;

    i32x4 acc[4][4];
#pragma unroll
    for (int i = 0; i < 4; ++i)
#pragma unroll
        for (int j = 0; j < 4; ++j)
#pragma unroll
            for (int r = 0; r < 4; ++r) acc[i][j][r] = 0;

    const char* a_g = (const char*)A + (size_t)m0 * EMBED;
    const char* b_g = (const char*)B + (size_t)n0 * EMBED;
    const int kc = lane >> 4;
    const int rr = lane & 15;

    for (int k0 = 0; k0 < EMBED; k0 += 128) {
#pragma unroll
        for (int c = 0; c < 2; ++c) {
            stage_rows8<256>(a_g + k0 + 64 * c, EMBED, As + c * 256 * 64, wave, lane);
            stage_rows8<128>(b_g + k0 + 64 * c, EMBED, Bs + c * 128 * 64, wave, lane);
        }
        __syncthreads();

#pragma unroll
        for (int c = 0; c < 2; ++c) {
            i32x4 af[4], bf[4];
#pragma unroll
            for (int i = 0; i < 4; ++i) af[i] = frag_i8(As + c * 256 * 64, wm * 64 + i * 16 + rr, kc);
#pragma unroll
            for (int j = 0; j < 4; ++j) bf[j] = frag_i8(Bs + c * 128 * 64, wn * 64 + j * 16 + rr, kc);
#pragma unroll
            for (int i = 0; i < 4; ++i)
#pragma unroll
                for (int j = 0; j < 4; ++j)
                    acc[i][j] = __builtin_amdgcn_mfma_i32_16x16x64_i8(af[i], bf[j], acc[i][j], 0, 0, 0);
        }
        __syncthreads();
    }

    // Write-only local selection epilogue (per-wave 64x64 — unchanged).
    const int lr = lane >> 4;
    const int lc = lane & 15;
    const int wslot = bx * 2 + wn;                    // 64 slots per row
    const unsigned long long grp = 0xFFFFull << (lr * 16);
    const unsigned long long low = (lane == 63) ? 0x7FFFFFFFFFFFFFFFull
                                                : ((1ull << lane) - 1);
#pragma unroll
    for (int i = 0; i < 4; ++i)
#pragma unroll
        for (int r = 0; r < 4; ++r) {
            const int row = m0 + wm * 64 + i * 16 + lr * 4 + r;
            float v[4];
            float vmax = -3.4e38f;
#pragma unroll
            for (int j = 0; j < 4; ++j) {
                v[j] = (float)acc[i][j][r] * SCLOGIT;
                vmax = fmaxf(vmax, v[j]);
            }
#pragma unroll
            for (int msk = 1; msk < 16; msk <<= 1)
                vmax = fmaxf(vmax, __shfl_xor(vmax, msk, 64));
            const float thr = vmax - MARGIN;
            int base = 0;
#pragma unroll
            for (int j = 0; j < 4; ++j) {
                const bool pred = v[j] > thr;
                const unsigned long long m = __ballot(pred) & grp;
                if (pred) {
                    const int pos = base + __popcll(m & low);
                    if (pos < KC)
                        cand[((size_t)row * 64 + wslot) * KC + pos] =
                            make_int2(n0 + wn * 64 + j * 16 + lc,
                                      __float_as_int(v[j]));
                }
                base += __popcll(m);
            }
            if (lc == 0) {
                tmax[(size_t)row * 64 + wslot] = vmax;
                cnts[(size_t)row * 64 + wslot] = base < KC ? base : KC;
            }
        }
}

// ---------------------------------------------------------------------------
// Final: global row max over 64 tile maxima, filter stored candidates,
// wave-parallel exact fp32 logits, softmax, blend fp32 X rows. 1 block/row.
// ---------------------------------------------------------------------------
__global__ __launch_bounds__(256) void sparse_out(const float* __restrict__ tmax,
                                                  const int* __restrict__ cnts,
                                                  const int2* __restrict__ cand,
                                                  const float* __restrict__ Qf,
                                                  const float* __restrict__ X,
                                                  float* __restrict__ out) {
    const int t = threadIdx.x;
    const int lane = t & 63, wave = t >> 6;
    const int row = blockIdx.x;

    __shared__ float gmax_s;
    __shared__ int   n2;
    __shared__ int   list[CAP];
    __shared__ float ll[CAP];
    if (t == 0) n2 = 0;

    // global row max over 64 tile maxima (wave 0)
    float gm = -3.4e38f;
    if (t < 64) gm = tmax[(size_t)row * 64 + t];
#pragma unroll
    for (int off = 32; off >= 1; off >>= 1) gm = fmaxf(gm, __shfl_xor(gm, off, 64));
    if (t == 0) gmax_s = gm;
    __syncthreads();
    const float thr = gmax_s - MARGIN;

    // filter stored candidates (64 slots x KC entries)
    for (int e = t; e < 64 * KC; e += 256) {
        const int s = e >> 3, k = e & (KC - 1);
        if (k < cnts[(size_t)row * 64 + s]) {
            const int2 c = cand[((size_t)row * 64 + s) * KC + k];
            if (__int_as_float(c.y) > thr) {
                const int p = atomicAdd(&n2, 1);   // LDS atomic
                if (p < CAP) list[p] = c.x;
            }
        }
    }
    __syncthreads();
    const int nc = min(n2, CAP);

    // exact logits, wave-parallel: candidate c handled by wave (c & 3)
    float4 q[4];
#pragma unroll
    for (int i = 0; i < 4; ++i)
        q[i] = *(const float4*)&Qf[(size_t)row * EMBED + lane * 16 + i * 4];
    for (int c = wave; c < nc; c += 4) {
        const float* xp = &X[(size_t)list[c] * EMBED + lane * 16];
        float p = 0.f;
#pragma unroll
        for (int i = 0; i < 4; ++i) {
            const float4 x4 = *(const float4*)(xp + i * 4);
            p += q[i].x * x4.x + q[i].y * x4.y + q[i].z * x4.z + q[i].w * x4.w;
        }
#pragma unroll
        for (int off = 32; off >= 1; off >>= 1) p += __shfl_xor(p, off, 64);
        if (lane == 0) ll[c] = p * 0.03125f;
    }
    __syncthreads();

    // exact softmax over candidates (redundant per thread; nc is tiny)
    float mt = -3.4e38f;
    for (int c = 0; c < nc; ++c) mt = fmaxf(mt, ll[c]);
    float wsum = 0.f;
    for (int c = 0; c < nc; ++c) wsum += __expf(ll[c] - mt);
    const float inv = 1.0f / wsum;

    float4 o = {0.f, 0.f, 0.f, 0.f};
    for (int c = 0; c < nc; ++c) {
        const float w = __expf(ll[c] - mt);
        const float4 xj = *(const float4*)&X[(size_t)list[c] * EMBED + t * 4];
        o.x += w * xj.x; o.y += w * xj.y; o.z += w * xj.z; o.w += w * xj.w;
    }
    o.x *= inv; o.y *= inv; o.z *= inv; o.w *= inv;
    *(float4*)&out[(size_t)row * EMBED + t * 4] = o;
}

extern "C" void kernel_launch(void* const* d_in, const int* in_sizes, int n_in,
                              void* d_out, int out_size, void* d_ws, size_t ws_size,
                              hipStream_t stream) {
    const float* X  = (const float*)d_in[0];  // [4096,1024]
    const float* Wq = (const float*)d_in[1];  // [1024,1024]
    const float* Wk = (const float*)d_in[2];  // [1024,1024]
    float* out = (float*)d_out;

    char* ws = (char*)d_ws;
    const size_t MB = 1024 * 1024;
    signed char*    Xi8 = (signed char*)(ws + 16 * MB);     // 4 MB
    float*          Qf  = (float*)(ws + 20 * MB);           // 16 MB
    signed char*    Qi8 = (signed char*)(ws + 36 * MB);     // 4 MB
    float* tmax = (float*)(ws + 40 * MB);                   // 1 MB
    int*   cnts = (int*)(ws + 41 * MB);                     // 1 MB
    int2*  cand = (int2*)(ws + 42 * MB);                    // 16 MB
    unsigned short* Wqhi = (unsigned short*)(ws + 58 * MB);
    unsigned short* Wqlo = (unsigned short*)(ws + 60 * MB);
    unsigned short* Wkhi = (unsigned short*)(ws + 62 * MB);
    unsigned short* Wklo = (unsigned short*)(ws + 64 * MB);
    unsigned short* Thi  = (unsigned short*)(ws + 66 * MB);
    unsigned short* Tlo  = (unsigned short*)(ws + 68 * MB);
    // T fp32 partials (4 x 4 MB) alias the cand region: written/consumed
    // (t_gemm -> t_merge) strictly before gemm_i8_scores writes cand.
    float* Tpart = (float*)(ws + 42 * MB);                  // 16 MB

    // 1) prep: W hi/lo splits + X -> i8
    prep<<<6144, 256, 0, stream>>>(
        (const float4*)X, (const float4*)Wq, (const float4*)Wk, (char4*)Xi8,
        (ushort4*)Wqhi, (ushort4*)Wqlo, (ushort4*)Wkhi, (ushort4*)Wklo);

    // 2) split-K=4 T-partials (T = Wk @ Wq^T = M^T)
    t_gemm<<<dim3(16, 16, 4), 256, 0, stream>>>(
        Wkhi, Wklo, Wqhi, Wqlo, Tpart);

    // 3) merge partials -> split bf16 T
    t_merge<<<1024, 256, 0, stream>>>((const float4*)Tpart,
                                      (ushort4*)Thi, (ushort4*)Tlo);

    // 4) Qf = X @ T^T (= X @ M): pipelined fp32-A split, dbuf B, XCD swizzle
    qf_gemm<<<dim3(16, 32), 512, 0, stream>>>(
        X, Thi, Tlo, Qf, Qi8);

    // 5) i8 cheap scores (256x128 tile, m97 2-barrier, K-step 128)
    gemm_i8_scores<<<dim3(32, 16), 512, 0, stream>>>(Qi8, Xi8, tmax, cnts, cand);

    // 6) exact sparse softmax + gather
    sparse_out<<<NTOK, 256, 0, stream>>>(tmax, cnts, cand, Qf, X, out);
}

// Round 5
// 173.654 us; speedup vs baseline: 1.0426x; 1.0282x over previous
//
#include <hip/hip_runtime.h>

#define EMBED 1024
#define NTOK  4096
#define MARGIN 256.0f   // i8 cheap-logit error sigma ~22; 2*5.5sigma + window
#define KC     8        // candidate slots per (row, wave-tile)
#define CAP    128      // final per-row candidate cap

// i8 scales: Xi8 = round(X * 127/5), Qi8 = round(Q' * 127/8192)
#define SX_INV 25.4f
#define SQ_INV 0.0155029296875f
#define SCLOGIT 0.07936198f   // (8192/127)*(5/127)/32

typedef short  s16x8 __attribute__((ext_vector_type(8)));
typedef float  f32x4 __attribute__((ext_vector_type(4)));
typedef int    i32x4 __attribute__((ext_vector_type(4)));

// ---- bf16 helpers (RNE) ----------------------------------------------------
__device__ __forceinline__ unsigned short f2bf(float f) {
    unsigned int u = __float_as_uint(f);
    u = (u + 0x7FFFu + ((u >> 16) & 1u)) >> 16;
    return (unsigned short)u;
}
__device__ __forceinline__ float bf2f(unsigned short h) {
    return __uint_as_float(((unsigned int)h) << 16);
}

// ---- async 16B global->LDS -------------------------------------------------
__device__ __forceinline__ void async16(const void* g, void* l) {
    __builtin_amdgcn_global_load_lds(
        (const __attribute__((address_space(1))) unsigned int*)g,
        (__attribute__((address_space(3))) unsigned int*)l, 16, 0, 0);
}

// Stage ROWS x 64-byte rows (row-major, swizzled 16B chunks) into LDS.
// ld in BYTES. 4-wave (256-thread) version.
template<int ROWS>
__device__ __forceinline__ void stage_rows(const char* __restrict__ g,
                                           int ld, char* lds, int wave, int lane) {
#pragma unroll
    for (int r = 0; r < ROWS / 64; ++r) {
        const int row0 = (wave * (ROWS / 64) + r) * 16;   // wave-uniform
        const int r_loc = lane >> 2;
        const int kc = (lane - (lane >> 3)) & 3;          // (slot - r_loc/2) & 3
        const char* gp = g + (size_t)(row0 + r_loc) * ld + kc * 16;
        char* lp = lds + row0 * 64;                       // wave-uniform base
        async16(gp, lp);
    }
}

// 8-wave (512-thread) version. ROWS must be a multiple of 128.
template<int ROWS>
__device__ __forceinline__ void stage_rows8(const char* __restrict__ g,
                                            int ld, char* lds, int wave, int lane) {
#pragma unroll
    for (int r = 0; r < ROWS / 128; ++r) {
        const int row0 = (wave * (ROWS / 128) + r) * 16;  // wave-uniform
        const int r_loc = lane >> 2;
        const int kc = (lane - (lane >> 3)) & 3;
        const char* gp = g + (size_t)(row0 + r_loc) * ld + kc * 16;
        char* lp = lds + row0 * 64;                       // wave-uniform base
        async16(gp, lp);
    }
}

__device__ __forceinline__ int frag_slot(int row, int kc) {
    return (kc + ((row & 15) >> 1)) & 3;
}
__device__ __forceinline__ s16x8 frag_bf16(const char* lds, int row, int kc) {
    return *(const s16x8*)(lds + row * 64 + frag_slot(row, kc) * 16);
}
__device__ __forceinline__ i32x4 frag_i8(const char* lds, int row, int kc) {
    return *(const i32x4*)(lds + row * 64 + frag_slot(row, kc) * 16);
}

// ---------------------------------------------------------------------------
// prep: X -> bf16 hi/lo + i8; Wq, Wk -> bf16 hi/lo. 6144 blocks x 256 thr.
// (Xhi/Xlo re-materialized: qf_gemm consumes them via global_load_lds with
// zero conversion VALU — R4 showed in-kernel cvt was qf's bottleneck.)
// ---------------------------------------------------------------------------
__global__ __launch_bounds__(256) void prep(
        const float4* __restrict__ X, const float4* __restrict__ Wq,
        const float4* __restrict__ Wk,
        ushort4* __restrict__ Xhi, ushort4* __restrict__ Xlo, char4* __restrict__ Xi8,
        ushort4* __restrict__ Wqhi, ushort4* __restrict__ Wqlo,
        ushort4* __restrict__ Wkhi, ushort4* __restrict__ Wklo) {
    const int NX4 = NTOK * EMBED / 4;
    const int NW4 = EMBED * EMBED / 4;
    const int n = blockIdx.x * 256 + threadIdx.x;

    const float4* src;
    ushort4 *hi, *lo;
    int idx;
    bool do_i8 = false;
    if (n < NX4) {
        src = X; hi = Xhi; lo = Xlo; idx = n; do_i8 = true;
    } else if (n < NX4 + NW4) {
        src = Wq; hi = Wqhi; lo = Wqlo; idx = n - NX4;
    } else {
        src = Wk; hi = Wkhi; lo = Wklo; idx = n - NX4 - NW4;
    }
    const float4 v = src[idx];
    ushort4 h, l;
    h.x = f2bf(v.x); l.x = f2bf(v.x - bf2f(h.x));
    h.y = f2bf(v.y); l.y = f2bf(v.y - bf2f(h.y));
    h.z = f2bf(v.z); l.z = f2bf(v.z - bf2f(h.z));
    h.w = f2bf(v.w); l.w = f2bf(v.w - bf2f(h.w));
    hi[idx] = h; lo[idx] = l;
    if (do_i8) {
        char4 c;
        c.x = (signed char)(int)rintf(fminf(fmaxf(v.x * SX_INV, -127.f), 127.f));
        c.y = (signed char)(int)rintf(fminf(fmaxf(v.y * SX_INV, -127.f), 127.f));
        c.z = (signed char)(int)rintf(fminf(fmaxf(v.z * SX_INV, -127.f), 127.f));
        c.w = (signed char)(int)rintf(fminf(fmaxf(v.w * SX_INV, -127.f), 127.f));
        Xi8[idx] = c;
    }
}

// ---------------------------------------------------------------------------
// Split-K=4 T-partial GEMM. T = Wk @ Wq^T, 3-pass split bf16, 64x64 tile,
// K-slice = 256 per z. Partials to Cpart[z] (fp32, no atomics).
// grid (16,16,4), 256 threads.
// ---------------------------------------------------------------------------
__global__ __launch_bounds__(256) void t_gemm(
        const unsigned short* __restrict__ Ahi, const unsigned short* __restrict__ Alo,
        const unsigned short* __restrict__ Bhi, const unsigned short* __restrict__ Blo,
        float* __restrict__ Cpart)
{
    constexpr int BM = 64, BN = 64, NCH = 2;
    __shared__ __align__(16) char As_hi[BM * 64 * NCH];
    __shared__ __align__(16) char Bs_hi[BN * 64 * NCH];
    __shared__ __align__(16) char As_lo[BM * 64 * NCH];
    __shared__ __align__(16) char Bs_lo[BN * 64 * NCH];

    const int t = threadIdx.x;
    const int z = blockIdx.z;
    const int lane = t & 63, wave = t >> 6;
    const int wm = wave >> 1, wn = wave & 1;
    const int m0 = blockIdx.y * BM, n0 = blockIdx.x * BN;

    f32x4 acc[2][2];
#pragma unroll
    for (int i = 0; i < 2; ++i)
#pragma unroll
        for (int j = 0; j < 2; ++j)
#pragma unroll
            for (int r = 0; r < 4; ++r) acc[i][j][r] = 0.f;

    const char* ah_g = (const char*)(Ahi + (size_t)m0 * EMBED);
    const char* bh_g = (const char*)(Bhi + (size_t)n0 * EMBED);
    const char* al_g = (const char*)(Alo + (size_t)m0 * EMBED);
    const char* bl_g = (const char*)(Blo + (size_t)n0 * EMBED);

    const int kc = lane >> 4;
    const int rr = lane & 15;
    const int kbeg = z * 256;

    for (int k0 = kbeg; k0 < kbeg + 256; k0 += 32 * NCH) {
#pragma unroll
        for (int c = 0; c < NCH; ++c) {
            const int kb = (k0 + 32 * c) * 2;
            stage_rows<BM>(ah_g + kb, EMBED * 2, As_hi + c * BM * 64, wave, lane);
            stage_rows<BN>(bh_g + kb, EMBED * 2, Bs_hi + c * BN * 64, wave, lane);
            stage_rows<BM>(al_g + kb, EMBED * 2, As_lo + c * BM * 64, wave, lane);
            stage_rows<BN>(bl_g + kb, EMBED * 2, Bs_lo + c * BN * 64, wave, lane);
        }
        __syncthreads();

#pragma unroll
        for (int c = 0; c < NCH; ++c) {
            s16x8 ah[2], bh[2], al[2], bl[2];
#pragma unroll
            for (int i = 0; i < 2; ++i)
                ah[i] = frag_bf16(As_hi + c * BM * 64, wm * 32 + i * 16 + rr, kc);
#pragma unroll
            for (int j = 0; j < 2; ++j)
                bh[j] = frag_bf16(Bs_hi + c * BN * 64, wn * 32 + j * 16 + rr, kc);
#pragma unroll
            for (int i = 0; i < 2; ++i)
                al[i] = frag_bf16(As_lo + c * BM * 64, wm * 32 + i * 16 + rr, kc);
#pragma unroll
            for (int j = 0; j < 2; ++j)
                bl[j] = frag_bf16(Bs_lo + c * BN * 64, wn * 32 + j * 16 + rr, kc);

#pragma unroll
            for (int i = 0; i < 2; ++i)
#pragma unroll
                for (int j = 0; j < 2; ++j)
                    acc[i][j] = __builtin_amdgcn_mfma_f32_16x16x32_bf16(ah[i], bh[j], acc[i][j], 0, 0, 0);
#pragma unroll
            for (int i = 0; i < 2; ++i)
#pragma unroll
                for (int j = 0; j < 2; ++j)
                    acc[i][j] = __builtin_amdgcn_mfma_f32_16x16x32_bf16(ah[i], bl[j], acc[i][j], 0, 0, 0);
#pragma unroll
            for (int i = 0; i < 2; ++i)
#pragma unroll
                for (int j = 0; j < 2; ++j)
                    acc[i][j] = __builtin_amdgcn_mfma_f32_16x16x32_bf16(al[i], bh[j], acc[i][j], 0, 0, 0);
        }
        __syncthreads();
    }

    // fp32 partial epilogue into slice z
    const int lr = lane >> 4;
    const int lc = lane & 15;
    float* Cz = Cpart + (size_t)z * EMBED * EMBED;
#pragma unroll
    for (int i = 0; i < 2; ++i)
#pragma unroll
        for (int j = 0; j < 2; ++j)
#pragma unroll
            for (int r = 0; r < 4; ++r) {
                const int row = m0 + wm * 32 + i * 16 + lr * 4 + r;
                const int col = n0 + wn * 32 + j * 16 + lc;
                Cz[(size_t)row * EMBED + col] = acc[i][j][r];
            }
}

// ---------------------------------------------------------------------------
// Merge 4 fp32 T-partials -> split bf16 (Thi, Tlo). 1024 blocks x 256 thr.
// ---------------------------------------------------------------------------
__global__ __launch_bounds__(256) void t_merge(const float4* __restrict__ P,
                                               ushort4* __restrict__ Thi,
                                               ushort4* __restrict__ Tlo) {
    const int idx = blockIdx.x * 256 + threadIdx.x;   // over EMBED*EMBED/4
    const int S = EMBED * EMBED / 4;
    const float4 a = P[idx], b = P[idx + S], c = P[idx + 2 * S], d = P[idx + 3 * S];
    float4 s;
    s.x = (a.x + b.x) + (c.x + d.x);
    s.y = (a.y + b.y) + (c.y + d.y);
    s.z = (a.z + b.z) + (c.z + d.z);
    s.w = (a.w + b.w) + (c.w + d.w);
    ushort4 h, l;
    h.x = f2bf(s.x); l.x = f2bf(s.x - bf2f(h.x));
    h.y = f2bf(s.y); l.y = f2bf(s.y - bf2f(h.y));
    h.z = f2bf(s.z); l.z = f2bf(s.z - bf2f(h.z));
    h.w = f2bf(s.w); l.w = f2bf(s.w - bf2f(h.w));
    Thi[idx] = h; Tlo[idx] = l;
}

// ---------------------------------------------------------------------------
// Qf GEMM: Qf[4096,1024] = X[4096,1024] @ T^T, 3-pass split bf16 (hh+hl+lh).
// ALL operands bf16 in memory, staged via global_load_lds — zero cvt VALU
// (R4: in-kernel fp32->bf16 cvt was 37% VALUBusy vs 23% MfmaUtil).
// m97-style 2-barrier loop (pipelining measured neutral R3/R4).
// 512 threads / 8 waves, per-wave 32x32 tile, LDS 48 KB -> 3 blocks/CU
// (24 waves/CU capacity, 2x R1's 12). XCD-aware bijective swizzle.
// Epilogue: fp32 Qf + i8 Qi8.
// ---------------------------------------------------------------------------
__global__ __launch_bounds__(512) void qf_gemm(
        const unsigned short* __restrict__ Ahi, const unsigned short* __restrict__ Alo,
        const unsigned short* __restrict__ Bhi, const unsigned short* __restrict__ Blo,
        float* __restrict__ C, signed char* __restrict__ Ci8)
{
    constexpr int BM = 128, BN = 64, NCH = 2;             // K-step = 64
    __shared__ __align__(16) char As_hi[BM * 64 * NCH];   // 16 KB
    __shared__ __align__(16) char As_lo[BM * 64 * NCH];   // 16 KB
    __shared__ __align__(16) char Bs_hi[BN * 64 * NCH];   // 8 KB
    __shared__ __align__(16) char Bs_lo[BN * 64 * NCH];   // 8 KB

    const int t = threadIdx.x;
    const int lane = t & 63, wave = t >> 6;
    const int wm = wave >> 1, wn = wave & 1;              // 4x2 wave grid

    // XCD swizzle: 512 blocks = 8 XCD x 64; per XCD 4 m-panels x 16 n-tiles
    const int bid = blockIdx.y * 16 + blockIdx.x;
    const int g = bid & 7, ii = bid >> 3;                 // ii in 0..63
    const int m0 = (g * 4 + (ii >> 4)) * BM;
    const int n0 = (ii & 15) * BN;

    f32x4 acc[2][2];
#pragma unroll
    for (int i = 0; i < 2; ++i)
#pragma unroll
        for (int j = 0; j < 2; ++j)
#pragma unroll
            for (int r = 0; r < 4; ++r) acc[i][j][r] = 0.f;

    const char* ah_g = (const char*)(Ahi + (size_t)m0 * EMBED);
    const char* al_g = (const char*)(Alo + (size_t)m0 * EMBED);

    // B staging: waves 0-3 stage Bs_hi, waves 4-7 stage Bs_lo (16 rows each)
    const unsigned short* bsrc = (wave < 4) ? Bhi : Blo;
    char* bdst = (wave < 4) ? Bs_hi : Bs_lo;
    const int w4 = wave & 3;
    const int brow0 = w4 * 16;
    const int b_rloc = lane >> 2;
    const int b_kc = (lane - (lane >> 3)) & 3;
    const char* bg = (const char*)(bsrc + (size_t)(n0 + brow0 + b_rloc) * EMBED) + b_kc * 16;
    char* b_lds = bdst + brow0 * 64;                      // wave-uniform

    const int kc = lane >> 4;
    const int rr = lane & 15;

    for (int k0 = 0; k0 < EMBED; k0 += 32 * NCH) {
#pragma unroll
        for (int c = 0; c < NCH; ++c) {
            const int kb = (k0 + 32 * c) * 2;
            stage_rows8<BM>(ah_g + kb, EMBED * 2, As_hi + c * BM * 64, wave, lane);
            stage_rows8<BM>(al_g + kb, EMBED * 2, As_lo + c * BM * 64, wave, lane);
            async16(bg + kb, b_lds + c * BN * 64);
        }
        __syncthreads();

#pragma unroll
        for (int c = 0; c < NCH; ++c) {
            s16x8 ah[2], bh[2], al[2], bl[2];
#pragma unroll
            for (int i = 0; i < 2; ++i)
                ah[i] = frag_bf16(As_hi + c * BM * 64, wm * 32 + i * 16 + rr, kc);
#pragma unroll
            for (int j = 0; j < 2; ++j)
                bh[j] = frag_bf16(Bs_hi + c * BN * 64, wn * 32 + j * 16 + rr, kc);
#pragma unroll
            for (int i = 0; i < 2; ++i)
                al[i] = frag_bf16(As_lo + c * BM * 64, wm * 32 + i * 16 + rr, kc);
#pragma unroll
            for (int j = 0; j < 2; ++j)
                bl[j] = frag_bf16(Bs_lo + c * BN * 64, wn * 32 + j * 16 + rr, kc);

#pragma unroll
            for (int i = 0; i < 2; ++i)
#pragma unroll
                for (int j = 0; j < 2; ++j)
                    acc[i][j] = __builtin_amdgcn_mfma_f32_16x16x32_bf16(ah[i], bh[j], acc[i][j], 0, 0, 0);
#pragma unroll
            for (int i = 0; i < 2; ++i)
#pragma unroll
                for (int j = 0; j < 2; ++j)
                    acc[i][j] = __builtin_amdgcn_mfma_f32_16x16x32_bf16(ah[i], bl[j], acc[i][j], 0, 0, 0);
#pragma unroll
            for (int i = 0; i < 2; ++i)
#pragma unroll
                for (int j = 0; j < 2; ++j)
                    acc[i][j] = __builtin_amdgcn_mfma_f32_16x16x32_bf16(al[i], bh[j], acc[i][j], 0, 0, 0);
        }
        __syncthreads();
    }

    // Epilogue: C/D layout col=lane&15, row=(lane>>4)*4+reg
    const int lr = lane >> 4;
    const int lc = lane & 15;
#pragma unroll
    for (int i = 0; i < 2; ++i)
#pragma unroll
        for (int j = 0; j < 2; ++j)
#pragma unroll
            for (int r = 0; r < 4; ++r) {
                const int row = m0 + wm * 32 + i * 16 + lr * 4 + r;
                const int col = n0 + wn * 32 + j * 16 + lc;
                const float v = acc[i][j][r];
                const size_t idx = (size_t)row * EMBED + col;
                C[idx] = v;
                const float q = fminf(fmaxf(v * SQ_INV, -127.f), 127.f);
                Ci8[idx] = (signed char)(int)rintf(q);
            }
}

// ---------------------------------------------------------------------------
// i8 scores GEMM + write-only candidate selection. m97 2-barrier loop,
// K-step 128. 256x128 tile, 512 threads / 8 waves, LDS 48 KB -> 2 blocks/CU,
// 512 blocks fully co-resident. XCD swizzle: 8 XCD x (2 m-panels x 32 n).
// ---------------------------------------------------------------------------
__global__ __launch_bounds__(512, 4) void gemm_i8_scores(
        const signed char* __restrict__ A,   // Qi8 [NTOK, EMBED]
        const signed char* __restrict__ B,   // Xi8 [NTOK, EMBED]
        float* __restrict__ tmax, int* __restrict__ cnts, int2* __restrict__ cand)
{
    __shared__ __align__(16) char As[256 * 64 * 2];   // 32 KB
    __shared__ __align__(16) char Bs[128 * 64 * 2];   // 16 KB

    const int t = threadIdx.x;
    const int lane = t & 63, wave = t >> 6;
    const int wm = wave >> 1, wn = wave & 1;          // 4x2 wave grid

    // XCD swizzle: 512 blocks = 8 XCD x 64; per XCD 2 m-panels x 32 n-tiles
    const int bid = blockIdx.y * 32 + blockIdx.x;
    const int g = bid & 7, ii = bid >> 3;             // ii in 0..63
    const int by = g * 2 + (ii >> 5);
    const int bx = ii & 31;
    const int m0 = by * 256, n0 = bx * 128;

    i32x4 acc[4][4];
#pragma unroll
    for (int i = 0; i < 4; ++i)
#pragma unroll
        for (int j = 0; j < 4; ++j)
#pragma unroll
            for (int r = 0; r < 4; ++r) acc[i][j][r] = 0;

    const char* a_g = (const char*)A + (size_t)m0 * EMBED;
    const char* b_g = (const char*)B + (size_t)n0 * EMBED;
    const int kc = lane >> 4;
    const int rr = lane & 15;

    for (int k0 = 0; k0 < EMBED; k0 += 128) {
#pragma unroll
        for (int c = 0; c < 2; ++c) {
            stage_rows8<256>(a_g + k0 + 64 * c, EMBED, As + c * 256 * 64, wave, lane);
            stage_rows8<128>(b_g + k0 + 64 * c, EMBED, Bs + c * 128 * 64, wave, lane);
        }
        __syncthreads();

#pragma unroll
        for (int c = 0; c < 2; ++c) {
            i32x4 af[4], bf[4];
#pragma unroll
            for (int i = 0; i < 4; ++i) af[i] = frag_i8(As + c * 256 * 64, wm * 64 + i * 16 + rr, kc);
#pragma unroll
            for (int j = 0; j < 4; ++j) bf[j] = frag_i8(Bs + c * 128 * 64, wn * 64 + j * 16 + rr, kc);
#pragma unroll
            for (int i = 0; i < 4; ++i)
#pragma unroll
                for (int j = 0; j < 4; ++j)
                    acc[i][j] = __builtin_amdgcn_mfma_i32_16x16x64_i8(af[i], bf[j], acc[i][j], 0, 0, 0);
        }
        __syncthreads();
    }

    // Write-only local selection epilogue (per-wave 64x64 — unchanged).
    const int lr = lane >> 4;
    const int lc = lane & 15;
    const int wslot = bx * 2 + wn;                    // 64 slots per row
    const unsigned long long grp = 0xFFFFull << (lr * 16);
    const unsigned long long low = (lane == 63) ? 0x7FFFFFFFFFFFFFFFull
                                                : ((1ull << lane) - 1);
#pragma unroll
    for (int i = 0; i < 4; ++i)
#pragma unroll
        for (int r = 0; r < 4; ++r) {
            const int row = m0 + wm * 64 + i * 16 + lr * 4 + r;
            float v[4];
            float vmax = -3.4e38f;
#pragma unroll
            for (int j = 0; j < 4; ++j) {
                v[j] = (float)acc[i][j][r] * SCLOGIT;
                vmax = fmaxf(vmax, v[j]);
            }
#pragma unroll
            for (int msk = 1; msk < 16; msk <<= 1)
                vmax = fmaxf(vmax, __shfl_xor(vmax, msk, 64));
            const float thr = vmax - MARGIN;
            int base = 0;
#pragma unroll
            for (int j = 0; j < 4; ++j) {
                const bool pred = v[j] > thr;
                const unsigned long long m = __ballot(pred) & grp;
                if (pred) {
                    const int pos = base + __popcll(m & low);
                    if (pos < KC)
                        cand[((size_t)row * 64 + wslot) * KC + pos] =
                            make_int2(n0 + wn * 64 + j * 16 + lc,
                                      __float_as_int(v[j]));
                }
                base += __popcll(m);
            }
            if (lc == 0) {
                tmax[(size_t)row * 64 + wslot] = vmax;
                cnts[(size_t)row * 64 + wslot] = base < KC ? base : KC;
            }
        }
}

// ---------------------------------------------------------------------------
// Final: global row max over 64 tile maxima, filter stored candidates,
// wave-parallel exact fp32 logits, softmax, blend fp32 X rows. 1 block/row.
// ---------------------------------------------------------------------------
__global__ __launch_bounds__(256) void sparse_out(const float* __restrict__ tmax,
                                                  const int* __restrict__ cnts,
                                                  const int2* __restrict__ cand,
                                                  const float* __restrict__ Qf,
                                                  const float* __restrict__ X,
                                                  float* __restrict__ out) {
    const int t = threadIdx.x;
    const int lane = t & 63, wave = t >> 6;
    const int row = blockIdx.x;

    __shared__ float gmax_s;
    __shared__ int   n2;
    __shared__ int   list[CAP];
    __shared__ float ll[CAP];
    if (t == 0) n2 = 0;

    // global row max over 64 tile maxima (wave 0)
    float gm = -3.4e38f;
    if (t < 64) gm = tmax[(size_t)row * 64 + t];
#pragma unroll
    for (int off = 32; off >= 1; off >>= 1) gm = fmaxf(gm, __shfl_xor(gm, off, 64));
    if (t == 0) gmax_s = gm;
    __syncthreads();
    const float thr = gmax_s - MARGIN;

    // filter stored candidates (64 slots x KC entries)
    for (int e = t; e < 64 * KC; e += 256) {
        const int s = e >> 3, k = e & (KC - 1);
        if (k < cnts[(size_t)row * 64 + s]) {
            const int2 c = cand[((size_t)row * 64 + s) * KC + k];
            if (__int_as_float(c.y) > thr) {
                const int p = atomicAdd(&n2, 1);   // LDS atomic
                if (p < CAP) list[p] = c.x;
            }
        }
    }
    __syncthreads();
    const int nc = min(n2, CAP);

    // exact logits, wave-parallel: candidate c handled by wave (c & 3)
    float4 q[4];
#pragma unroll
    for (int i = 0; i < 4; ++i)
        q[i] = *(const float4*)&Qf[(size_t)row * EMBED + lane * 16 + i * 4];
    for (int c = wave; c < nc; c += 4) {
        const float* xp = &X[(size_t)list[c] * EMBED + lane * 16];
        float p = 0.f;
#pragma unroll
        for (int i = 0; i < 4; ++i) {
            const float4 x4 = *(const float4*)(xp + i * 4);
            p += q[i].x * x4.x + q[i].y * x4.y + q[i].z * x4.z + q[i].w * x4.w;
        }
#pragma unroll
        for (int off = 32; off >= 1; off >>= 1) p += __shfl_xor(p, off, 64);
        if (lane == 0) ll[c] = p * 0.03125f;
    }
    __syncthreads();

    // exact softmax over candidates (redundant per thread; nc is tiny)
    float mt = -3.4e38f;
    for (int c = 0; c < nc; ++c) mt = fmaxf(mt, ll[c]);
    float wsum = 0.f;
    for (int c = 0; c < nc; ++c) wsum += __expf(ll[c] - mt);
    const float inv = 1.0f / wsum;

    float4 o = {0.f, 0.f, 0.f, 0.f};
    for (int c = 0; c < nc; ++c) {
        const float w = __expf(ll[c] - mt);
        const float4 xj = *(const float4*)&X[(size_t)list[c] * EMBED + t * 4];
        o.x += w * xj.x; o.y += w * xj.y; o.z += w * xj.z; o.w += w * xj.w;
    }
    o.x *= inv; o.y *= inv; o.z *= inv; o.w *= inv;
    *(float4*)&out[(size_t)row * EMBED + t * 4] = o;
}

extern "C" void kernel_launch(void* const* d_in, const int* in_sizes, int n_in,
                              void* d_out, int out_size, void* d_ws, size_t ws_size,
                              hipStream_t stream) {
    const float* X  = (const float*)d_in[0];  // [4096,1024]
    const float* Wq = (const float*)d_in[1];  // [1024,1024]
    const float* Wk = (const float*)d_in[2];  // [1024,1024]
    float* out = (float*)d_out;

    char* ws = (char*)d_ws;
    const size_t MB = 1024 * 1024;
    unsigned short* Xhi = (unsigned short*)(ws + 0 * MB);   // 8 MB
    unsigned short* Xlo = (unsigned short*)(ws + 8 * MB);   // 8 MB
    signed char*    Xi8 = (signed char*)(ws + 16 * MB);     // 4 MB
    float*          Qf  = (float*)(ws + 20 * MB);           // 16 MB
    signed char*    Qi8 = (signed char*)(ws + 36 * MB);     // 4 MB
    float* tmax = (float*)(ws + 40 * MB);                   // 1 MB
    int*   cnts = (int*)(ws + 41 * MB);                     // 1 MB
    int2*  cand = (int2*)(ws + 42 * MB);                    // 16 MB
    unsigned short* Wqhi = (unsigned short*)(ws + 58 * MB);
    unsigned short* Wqlo = (unsigned short*)(ws + 60 * MB);
    unsigned short* Wkhi = (unsigned short*)(ws + 62 * MB);
    unsigned short* Wklo = (unsigned short*)(ws + 64 * MB);
    unsigned short* Thi  = (unsigned short*)(ws + 66 * MB);
    unsigned short* Tlo  = (unsigned short*)(ws + 68 * MB);
    // T fp32 partials (4 x 4 MB) alias the cand region: written/consumed
    // (t_gemm -> t_merge) strictly before gemm_i8_scores writes cand.
    float* Tpart = (float*)(ws + 42 * MB);                  // 16 MB

    // 1) prep: X -> hi/lo/i8, Wq/Wk -> hi/lo
    prep<<<6144, 256, 0, stream>>>(
        (const float4*)X, (const float4*)Wq, (const float4*)Wk,
        (ushort4*)Xhi, (ushort4*)Xlo, (char4*)Xi8,
        (ushort4*)Wqhi, (ushort4*)Wqlo, (ushort4*)Wkhi, (ushort4*)Wklo);

    // 2) split-K=4 T-partials (T = Wk @ Wq^T = M^T)
    t_gemm<<<dim3(16, 16, 4), 256, 0, stream>>>(
        Wkhi, Wklo, Wqhi, Wqlo, Tpart);

    // 3) merge partials -> split bf16 T
    t_merge<<<1024, 256, 0, stream>>>((const float4*)Tpart,
                                      (ushort4*)Thi, (ushort4*)Tlo);

    // 4) Qf = X @ T^T (= X @ M): all-bf16 global_load_lds, 8 waves, 48 KB
    qf_gemm<<<dim3(16, 32), 512, 0, stream>>>(
        Xhi, Xlo, Thi, Tlo, Qf, Qi8);

    // 5) i8 cheap scores (256x128 tile, m97 2-barrier, K-step 128)
    gemm_i8_scores<<<dim3(32, 16), 512, 0, stream>>>(Qi8, Xi8, tmax, cnts, cand);

    // 6) exact sparse softmax + gather
    sparse_out<<<NTOK, 256, 0, stream>>>(tmax, cnts, cand, Qf, X, out);
}

// Round 6
// 169.123 us; speedup vs baseline: 1.0705x; 1.0268x over previous
//
#include <hip/hip_runtime.h>

#define EMBED 1024
#define NTOK  4096
#define MARGIN 256.0f   // i8 cheap-logit error sigma ~22; 2*5.5sigma + window
#define KC     8        // candidate slots per (row, wave-tile)
#define CAP    128      // final per-row candidate cap

// i8 scales: Xi8 = round(X * 127/5), Qi8 = round(Q' * 127/8192)
#define SX_INV 25.4f
#define SQ_INV 0.0155029296875f
#define SCLOGIT 0.07936198f   // (8192/127)*(5/127)/32

typedef short  s16x8 __attribute__((ext_vector_type(8)));
typedef float  f32x4 __attribute__((ext_vector_type(4)));
typedef int    i32x4 __attribute__((ext_vector_type(4)));

// ---- bf16 helpers (RNE) ----------------------------------------------------
__device__ __forceinline__ unsigned short f2bf(float f) {
    unsigned int u = __float_as_uint(f);
    u = (u + 0x7FFFu + ((u >> 16) & 1u)) >> 16;
    return (unsigned short)u;
}
__device__ __forceinline__ float bf2f(unsigned short h) {
    return __uint_as_float(((unsigned int)h) << 16);
}

// ---- async 16B global->LDS -------------------------------------------------
__device__ __forceinline__ void async16(const void* g, void* l) {
    __builtin_amdgcn_global_load_lds(
        (const __attribute__((address_space(1))) unsigned int*)g,
        (__attribute__((address_space(3))) unsigned int*)l, 16, 0, 0);
}

// Stage ROWS x 64-byte rows (row-major, swizzled 16B chunks) into LDS.
// ld in BYTES. 4-wave (256-thread) version.
template<int ROWS>
__device__ __forceinline__ void stage_rows(const char* __restrict__ g,
                                           int ld, char* lds, int wave, int lane) {
#pragma unroll
    for (int r = 0; r < ROWS / 64; ++r) {
        const int row0 = (wave * (ROWS / 64) + r) * 16;   // wave-uniform
        const int r_loc = lane >> 2;
        const int kc = (lane - (lane >> 3)) & 3;          // (slot - r_loc/2) & 3
        const char* gp = g + (size_t)(row0 + r_loc) * ld + kc * 16;
        char* lp = lds + row0 * 64;                       // wave-uniform base
        async16(gp, lp);
    }
}

// 8-wave (512-thread) version. ROWS must be a multiple of 128.
template<int ROWS>
__device__ __forceinline__ void stage_rows8(const char* __restrict__ g,
                                            int ld, char* lds, int wave, int lane) {
#pragma unroll
    for (int r = 0; r < ROWS / 128; ++r) {
        const int row0 = (wave * (ROWS / 128) + r) * 16;  // wave-uniform
        const int r_loc = lane >> 2;
        const int kc = (lane - (lane >> 3)) & 3;
        const char* gp = g + (size_t)(row0 + r_loc) * ld + kc * 16;
        char* lp = lds + row0 * 64;                       // wave-uniform base
        async16(gp, lp);
    }
}

__device__ __forceinline__ int frag_slot(int row, int kc) {
    return (kc + ((row & 15) >> 1)) & 3;
}
__device__ __forceinline__ s16x8 frag_bf16(const char* lds, int row, int kc) {
    return *(const s16x8*)(lds + row * 64 + frag_slot(row, kc) * 16);
}
__device__ __forceinline__ i32x4 frag_i8(const char* lds, int row, int kc) {
    return *(const i32x4*)(lds + row * 64 + frag_slot(row, kc) * 16);
}

// ---------------------------------------------------------------------------
// prep_w: W -> bf16 hi/lo splits only (the T GEMM's operands).
// 2048 blocks x 256 threads (~24 MB, ~4 us).
// ---------------------------------------------------------------------------
__global__ __launch_bounds__(256) void prep_w(
        const float4* __restrict__ Wq, const float4* __restrict__ Wk,
        ushort4* __restrict__ Wqhi, ushort4* __restrict__ Wqlo,
        ushort4* __restrict__ Wkhi, ushort4* __restrict__ Wklo) {
    const int NW4 = EMBED * EMBED / 4;
    const int n = blockIdx.x * 256 + threadIdx.x;

    const float4* src;
    ushort4 *hi, *lo;
    int idx;
    if (n < NW4) { src = Wq; hi = Wqhi; lo = Wqlo; idx = n; }
    else         { src = Wk; hi = Wkhi; lo = Wklo; idx = n - NW4; }
    const float4 v = src[idx];
    ushort4 h, l;
    h.x = f2bf(v.x); l.x = f2bf(v.x - bf2f(h.x));
    h.y = f2bf(v.y); l.y = f2bf(v.y - bf2f(h.y));
    h.z = f2bf(v.z); l.z = f2bf(v.z - bf2f(h.z));
    h.w = f2bf(v.w); l.w = f2bf(v.w - bf2f(h.w));
    hi[idx] = h; lo[idx] = l;
}

// ---------------------------------------------------------------------------
// Fused dispatch: split-K=4 T-partial GEMM (z<4) + X split (z>=4).
// T = Wk @ Wq^T, 3-pass split bf16, 64x64 tile, K-slice = 256 per z.
// Partials to Cpart[z] (fp32, no atomics). X-split blocks (BW-bound) overlap
// the latency-bound GEMM blocks (m114 MFMA+mem co-scheduling).
// grid (16,16,20), 256 threads.
// ---------------------------------------------------------------------------
__global__ __launch_bounds__(256) void t_fused(
        const unsigned short* __restrict__ Ahi, const unsigned short* __restrict__ Alo,
        const unsigned short* __restrict__ Bhi, const unsigned short* __restrict__ Blo,
        float* __restrict__ Cpart,
        const float4* __restrict__ X, ushort4* __restrict__ Xhi,
        ushort4* __restrict__ Xlo, char4* __restrict__ Xi8)
{
    constexpr int BM = 64, BN = 64, NCH = 2;
    __shared__ __align__(16) char As_hi[BM * 64 * NCH];
    __shared__ __align__(16) char Bs_hi[BN * 64 * NCH];
    __shared__ __align__(16) char As_lo[BM * 64 * NCH];
    __shared__ __align__(16) char Bs_lo[BN * 64 * NCH];

    const int t = threadIdx.x;
    const int z = blockIdx.z;

    if (z >= 4) {
        // ---- X split branch: 4096 blocks x 256 threads, 1 float4 each ----
        const int idx = (((z - 4) * 256) + blockIdx.y * 16 + blockIdx.x) * 256 + t;
        const float4 v = X[idx];
        ushort4 h, l;
        h.x = f2bf(v.x); l.x = f2bf(v.x - bf2f(h.x));
        h.y = f2bf(v.y); l.y = f2bf(v.y - bf2f(h.y));
        h.z = f2bf(v.z); l.z = f2bf(v.z - bf2f(h.z));
        h.w = f2bf(v.w); l.w = f2bf(v.w - bf2f(h.w));
        Xhi[idx] = h; Xlo[idx] = l;
        char4 c;
        c.x = (signed char)(int)rintf(fminf(fmaxf(v.x * SX_INV, -127.f), 127.f));
        c.y = (signed char)(int)rintf(fminf(fmaxf(v.y * SX_INV, -127.f), 127.f));
        c.z = (signed char)(int)rintf(fminf(fmaxf(v.z * SX_INV, -127.f), 127.f));
        c.w = (signed char)(int)rintf(fminf(fmaxf(v.w * SX_INV, -127.f), 127.f));
        Xi8[idx] = c;
        return;
    }

    // ---- T-partial GEMM branch: K in [z*256, z*256+256) ----
    const int lane = t & 63, wave = t >> 6;
    const int wm = wave >> 1, wn = wave & 1;
    const int m0 = blockIdx.y * BM, n0 = blockIdx.x * BN;

    f32x4 acc[2][2];
#pragma unroll
    for (int i = 0; i < 2; ++i)
#pragma unroll
        for (int j = 0; j < 2; ++j)
#pragma unroll
            for (int r = 0; r < 4; ++r) acc[i][j][r] = 0.f;

    const char* ah_g = (const char*)(Ahi + (size_t)m0 * EMBED);
    const char* bh_g = (const char*)(Bhi + (size_t)n0 * EMBED);
    const char* al_g = (const char*)(Alo + (size_t)m0 * EMBED);
    const char* bl_g = (const char*)(Blo + (size_t)n0 * EMBED);

    const int kc = lane >> 4;
    const int rr = lane & 15;
    const int kbeg = z * 256;

    for (int k0 = kbeg; k0 < kbeg + 256; k0 += 32 * NCH) {
#pragma unroll
        for (int c = 0; c < NCH; ++c) {
            const int kb = (k0 + 32 * c) * 2;
            stage_rows<BM>(ah_g + kb, EMBED * 2, As_hi + c * BM * 64, wave, lane);
            stage_rows<BN>(bh_g + kb, EMBED * 2, Bs_hi + c * BN * 64, wave, lane);
            stage_rows<BM>(al_g + kb, EMBED * 2, As_lo + c * BM * 64, wave, lane);
            stage_rows<BN>(bl_g + kb, EMBED * 2, Bs_lo + c * BN * 64, wave, lane);
        }
        __syncthreads();

#pragma unroll
        for (int c = 0; c < NCH; ++c) {
            s16x8 ah[2], bh[2], al[2], bl[2];
#pragma unroll
            for (int i = 0; i < 2; ++i)
                ah[i] = frag_bf16(As_hi + c * BM * 64, wm * 32 + i * 16 + rr, kc);
#pragma unroll
            for (int j = 0; j < 2; ++j)
                bh[j] = frag_bf16(Bs_hi + c * BN * 64, wn * 32 + j * 16 + rr, kc);
#pragma unroll
            for (int i = 0; i < 2; ++i)
                al[i] = frag_bf16(As_lo + c * BM * 64, wm * 32 + i * 16 + rr, kc);
#pragma unroll
            for (int j = 0; j < 2; ++j)
                bl[j] = frag_bf16(Bs_lo + c * BN * 64, wn * 32 + j * 16 + rr, kc);

#pragma unroll
            for (int i = 0; i < 2; ++i)
#pragma unroll
                for (int j = 0; j < 2; ++j)
                    acc[i][j] = __builtin_amdgcn_mfma_f32_16x16x32_bf16(ah[i], bh[j], acc[i][j], 0, 0, 0);
#pragma unroll
            for (int i = 0; i < 2; ++i)
#pragma unroll
                for (int j = 0; j < 2; ++j)
                    acc[i][j] = __builtin_amdgcn_mfma_f32_16x16x32_bf16(ah[i], bl[j], acc[i][j], 0, 0, 0);
#pragma unroll
            for (int i = 0; i < 2; ++i)
#pragma unroll
                for (int j = 0; j < 2; ++j)
                    acc[i][j] = __builtin_amdgcn_mfma_f32_16x16x32_bf16(al[i], bh[j], acc[i][j], 0, 0, 0);
        }
        __syncthreads();
    }

    // fp32 partial epilogue into slice z
    const int lr = lane >> 4;
    const int lc = lane & 15;
    float* Cz = Cpart + (size_t)z * EMBED * EMBED;
#pragma unroll
    for (int i = 0; i < 2; ++i)
#pragma unroll
        for (int j = 0; j < 2; ++j)
#pragma unroll
            for (int r = 0; r < 4; ++r) {
                const int row = m0 + wm * 32 + i * 16 + lr * 4 + r;
                const int col = n0 + wn * 32 + j * 16 + lc;
                Cz[(size_t)row * EMBED + col] = acc[i][j][r];
            }
}

// ---------------------------------------------------------------------------
// Merge 4 fp32 T-partials -> split bf16 (Thi, Tlo). 1024 blocks x 256 thr.
// ---------------------------------------------------------------------------
__global__ __launch_bounds__(256) void t_merge(const float4* __restrict__ P,
                                               ushort4* __restrict__ Thi,
                                               ushort4* __restrict__ Tlo) {
    const int idx = blockIdx.x * 256 + threadIdx.x;   // over EMBED*EMBED/4
    const int S = EMBED * EMBED / 4;
    const float4 a = P[idx], b = P[idx + S], c = P[idx + 2 * S], d = P[idx + 3 * S];
    float4 s;
    s.x = (a.x + b.x) + (c.x + d.x);
    s.y = (a.y + b.y) + (c.y + d.y);
    s.z = (a.z + b.z) + (c.z + d.z);
    s.w = (a.w + b.w) + (c.w + d.w);
    ushort4 h, l;
    h.x = f2bf(s.x); l.x = f2bf(s.x - bf2f(h.x));
    h.y = f2bf(s.y); l.y = f2bf(s.y - bf2f(h.y));
    h.z = f2bf(s.z); l.z = f2bf(s.z - bf2f(h.z));
    h.w = f2bf(s.w); l.w = f2bf(s.w - bf2f(h.w));
    Thi[idx] = h; Tlo[idx] = l;
}

// ---------------------------------------------------------------------------
// Qf GEMM: Qf[4096,1024] = X[4096,1024] @ T^T, 3-pass split bf16 (hh+hl+lh).
// ALL operands bf16 in memory, staged via global_load_lds — zero cvt VALU.
// m97-style 2-barrier loop. 512 threads / 8 waves, per-wave 32x32 tile,
// LDS 48 KB -> 3 blocks/CU. XCD-aware bijective swizzle.
// Epilogue: fp32 Qf + i8 Qi8. (R5 config — measured best.)
// ---------------------------------------------------------------------------
__global__ __launch_bounds__(512) void qf_gemm(
        const unsigned short* __restrict__ Ahi, const unsigned short* __restrict__ Alo,
        const unsigned short* __restrict__ Bhi, const unsigned short* __restrict__ Blo,
        float* __restrict__ C, signed char* __restrict__ Ci8)
{
    constexpr int BM = 128, BN = 64, NCH = 2;             // K-step = 64
    __shared__ __align__(16) char As_hi[BM * 64 * NCH];   // 16 KB
    __shared__ __align__(16) char As_lo[BM * 64 * NCH];   // 16 KB
    __shared__ __align__(16) char Bs_hi[BN * 64 * NCH];   // 8 KB
    __shared__ __align__(16) char Bs_lo[BN * 64 * NCH];   // 8 KB

    const int t = threadIdx.x;
    const int lane = t & 63, wave = t >> 6;
    const int wm = wave >> 1, wn = wave & 1;              // 4x2 wave grid

    // XCD swizzle: 512 blocks = 8 XCD x 64; per XCD 4 m-panels x 16 n-tiles
    const int bid = blockIdx.y * 16 + blockIdx.x;
    const int g = bid & 7, ii = bid >> 3;                 // ii in 0..63
    const int m0 = (g * 4 + (ii >> 4)) * BM;
    const int n0 = (ii & 15) * BN;

    f32x4 acc[2][2];
#pragma unroll
    for (int i = 0; i < 2; ++i)
#pragma unroll
        for (int j = 0; j < 2; ++j)
#pragma unroll
            for (int r = 0; r < 4; ++r) acc[i][j][r] = 0.f;

    const char* ah_g = (const char*)(Ahi + (size_t)m0 * EMBED);
    const char* al_g = (const char*)(Alo + (size_t)m0 * EMBED);

    // B staging: waves 0-3 stage Bs_hi, waves 4-7 stage Bs_lo (16 rows each)
    const unsigned short* bsrc = (wave < 4) ? Bhi : Blo;
    char* bdst = (wave < 4) ? Bs_hi : Bs_lo;
    const int w4 = wave & 3;
    const int brow0 = w4 * 16;
    const int b_rloc = lane >> 2;
    const int b_kc = (lane - (lane >> 3)) & 3;
    const char* bg = (const char*)(bsrc + (size_t)(n0 + brow0 + b_rloc) * EMBED) + b_kc * 16;
    char* b_lds = bdst + brow0 * 64;                      // wave-uniform

    const int kc = lane >> 4;
    const int rr = lane & 15;

    for (int k0 = 0; k0 < EMBED; k0 += 32 * NCH) {
#pragma unroll
        for (int c = 0; c < NCH; ++c) {
            const int kb = (k0 + 32 * c) * 2;
            stage_rows8<BM>(ah_g + kb, EMBED * 2, As_hi + c * BM * 64, wave, lane);
            stage_rows8<BM>(al_g + kb, EMBED * 2, As_lo + c * BM * 64, wave, lane);
            async16(bg + kb, b_lds + c * BN * 64);
        }
        __syncthreads();

#pragma unroll
        for (int c = 0; c < NCH; ++c) {
            s16x8 ah[2], bh[2], al[2], bl[2];
#pragma unroll
            for (int i = 0; i < 2; ++i)
                ah[i] = frag_bf16(As_hi + c * BM * 64, wm * 32 + i * 16 + rr, kc);
#pragma unroll
            for (int j = 0; j < 2; ++j)
                bh[j] = frag_bf16(Bs_hi + c * BN * 64, wn * 32 + j * 16 + rr, kc);
#pragma unroll
            for (int i = 0; i < 2; ++i)
                al[i] = frag_bf16(As_lo + c * BM * 64, wm * 32 + i * 16 + rr, kc);
#pragma unroll
            for (int j = 0; j < 2; ++j)
                bl[j] = frag_bf16(Bs_lo + c * BN * 64, wn * 32 + j * 16 + rr, kc);

#pragma unroll
            for (int i = 0; i < 2; ++i)
#pragma unroll
                for (int j = 0; j < 2; ++j)
                    acc[i][j] = __builtin_amdgcn_mfma_f32_16x16x32_bf16(ah[i], bh[j], acc[i][j], 0, 0, 0);
#pragma unroll
            for (int i = 0; i < 2; ++i)
#pragma unroll
                for (int j = 0; j < 2; ++j)
                    acc[i][j] = __builtin_amdgcn_mfma_f32_16x16x32_bf16(ah[i], bl[j], acc[i][j], 0, 0, 0);
#pragma unroll
            for (int i = 0; i < 2; ++i)
#pragma unroll
                for (int j = 0; j < 2; ++j)
                    acc[i][j] = __builtin_amdgcn_mfma_f32_16x16x32_bf16(al[i], bh[j], acc[i][j], 0, 0, 0);
        }
        __syncthreads();
    }

    // Epilogue: C/D layout col=lane&15, row=(lane>>4)*4+reg
    const int lr = lane >> 4;
    const int lc = lane & 15;
#pragma unroll
    for (int i = 0; i < 2; ++i)
#pragma unroll
        for (int j = 0; j < 2; ++j)
#pragma unroll
            for (int r = 0; r < 4; ++r) {
                const int row = m0 + wm * 32 + i * 16 + lr * 4 + r;
                const int col = n0 + wn * 32 + j * 16 + lc;
                const float v = acc[i][j][r];
                const size_t idx = (size_t)row * EMBED + col;
                C[idx] = v;
                const float q = fminf(fmaxf(v * SQ_INV, -127.f), 127.f);
                Ci8[idx] = (signed char)(int)rintf(q);
            }
}

// ---------------------------------------------------------------------------
// i8 scores GEMM + write-only candidate selection. m97 2-barrier loop,
// K-step 128. 256x128 tile, 512 threads / 8 waves, LDS 48 KB -> 2 blocks/CU,
// 512 blocks fully co-resident. XCD swizzle: 8 XCD x (2 m-panels x 32 n).
// (R4/R5 config — measured stable.)
// ---------------------------------------------------------------------------
__global__ __launch_bounds__(512, 4) void gemm_i8_scores(
        const signed char* __restrict__ A,   // Qi8 [NTOK, EMBED]
        const signed char* __restrict__ B,   // Xi8 [NTOK, EMBED]
        float* __restrict__ tmax, int* __restrict__ cnts, int2* __restrict__ cand)
{
    __shared__ __align__(16) char As[256 * 64 * 2];   // 32 KB
    __shared__ __align__(16) char Bs[128 * 64 * 2];   // 16 KB

    const int t = threadIdx.x;
    const int lane = t & 63, wave = t >> 6;
    const int wm = wave >> 1, wn = wave & 1;          // 4x2 wave grid

    // XCD swizzle: 512 blocks = 8 XCD x 64; per XCD 2 m-panels x 32 n-tiles
    const int bid = blockIdx.y * 32 + blockIdx.x;
    const int g = bid & 7, ii = bid >> 3;             // ii in 0..63
    const int by = g * 2 + (ii >> 5);
    const int bx = ii & 31;
    const int m0 = by * 256, n0 = bx * 128;

    i32x4 acc[4][4];
#pragma unroll
    for (int i = 0; i < 4; ++i)
#pragma unroll
        for (int j = 0; j < 4; ++j)
#pragma unroll
            for (int r = 0; r < 4; ++r) acc[i][j][r] = 0;

    const char* a_g = (const char*)A + (size_t)m0 * EMBED;
    const char* b_g = (const char*)B + (size_t)n0 * EMBED;
    const int kc = lane >> 4;
    const int rr = lane & 15;

    for (int k0 = 0; k0 < EMBED; k0 += 128) {
#pragma unroll
        for (int c = 0; c < 2; ++c) {
            stage_rows8<256>(a_g + k0 + 64 * c, EMBED, As + c * 256 * 64, wave, lane);
            stage_rows8<128>(b_g + k0 + 64 * c, EMBED, Bs + c * 128 * 64, wave, lane);
        }
        __syncthreads();

#pragma unroll
        for (int c = 0; c < 2; ++c) {
            i32x4 af[4], bf[4];
#pragma unroll
            for (int i = 0; i < 4; ++i) af[i] = frag_i8(As + c * 256 * 64, wm * 64 + i * 16 + rr, kc);
#pragma unroll
            for (int j = 0; j < 4; ++j) bf[j] = frag_i8(Bs + c * 128 * 64, wn * 64 + j * 16 + rr, kc);
#pragma unroll
            for (int i = 0; i < 4; ++i)
#pragma unroll
                for (int j = 0; j < 4; ++j)
                    acc[i][j] = __builtin_amdgcn_mfma_i32_16x16x64_i8(af[i], bf[j], acc[i][j], 0, 0, 0);
        }
        __syncthreads();
    }

    // Write-only local selection epilogue (per-wave 64x64 — unchanged).
    const int lr = lane >> 4;
    const int lc = lane & 15;
    const int wslot = bx * 2 + wn;                    // 64 slots per row
    const unsigned long long grp = 0xFFFFull << (lr * 16);
    const unsigned long long low = (lane == 63) ? 0x7FFFFFFFFFFFFFFFull
                                                : ((1ull << lane) - 1);
#pragma unroll
    for (int i = 0; i < 4; ++i)
#pragma unroll
        for (int r = 0; r < 4; ++r) {
            const int row = m0 + wm * 64 + i * 16 + lr * 4 + r;
            float v[4];
            float vmax = -3.4e38f;
#pragma unroll
            for (int j = 0; j < 4; ++j) {
                v[j] = (float)acc[i][j][r] * SCLOGIT;
                vmax = fmaxf(vmax, v[j]);
            }
#pragma unroll
            for (int msk = 1; msk < 16; msk <<= 1)
                vmax = fmaxf(vmax, __shfl_xor(vmax, msk, 64));
            const float thr = vmax - MARGIN;
            int base = 0;
#pragma unroll
            for (int j = 0; j < 4; ++j) {
                const bool pred = v[j] > thr;
                const unsigned long long m = __ballot(pred) & grp;
                if (pred) {
                    const int pos = base + __popcll(m & low);
                    if (pos < KC)
                        cand[((size_t)row * 64 + wslot) * KC + pos] =
                            make_int2(n0 + wn * 64 + j * 16 + lc,
                                      __float_as_int(v[j]));
                }
                base += __popcll(m);
            }
            if (lc == 0) {
                tmax[(size_t)row * 64 + wslot] = vmax;
                cnts[(size_t)row * 64 + wslot] = base < KC ? base : KC;
            }
        }
}

// ---------------------------------------------------------------------------
// Final: global row max over 64 tile maxima, filter stored candidates,
// wave-parallel exact fp32 logits, softmax, blend fp32 X rows. 1 block/row.
// ---------------------------------------------------------------------------
__global__ __launch_bounds__(256) void sparse_out(const float* __restrict__ tmax,
                                                  const int* __restrict__ cnts,
                                                  const int2* __restrict__ cand,
                                                  const float* __restrict__ Qf,
                                                  const float* __restrict__ X,
                                                  float* __restrict__ out) {
    const int t = threadIdx.x;
    const int lane = t & 63, wave = t >> 6;
    const int row = blockIdx.x;

    __shared__ float gmax_s;
    __shared__ int   n2;
    __shared__ int   list[CAP];
    __shared__ float ll[CAP];
    if (t == 0) n2 = 0;

    // global row max over 64 tile maxima (wave 0)
    float gm = -3.4e38f;
    if (t < 64) gm = tmax[(size_t)row * 64 + t];
#pragma unroll
    for (int off = 32; off >= 1; off >>= 1) gm = fmaxf(gm, __shfl_xor(gm, off, 64));
    if (t == 0) gmax_s = gm;
    __syncthreads();
    const float thr = gmax_s - MARGIN;

    // filter stored candidates (64 slots x KC entries)
    for (int e = t; e < 64 * KC; e += 256) {
        const int s = e >> 3, k = e & (KC - 1);
        if (k < cnts[(size_t)row * 64 + s]) {
            const int2 c = cand[((size_t)row * 64 + s) * KC + k];
            if (__int_as_float(c.y) > thr) {
                const int p = atomicAdd(&n2, 1);   // LDS atomic
                if (p < CAP) list[p] = c.x;
            }
        }
    }
    __syncthreads();
    const int nc = min(n2, CAP);

    // exact logits, wave-parallel: candidate c handled by wave (c & 3)
    float4 q[4];
#pragma unroll
    for (int i = 0; i < 4; ++i)
        q[i] = *(const float4*)&Qf[(size_t)row * EMBED + lane * 16 + i * 4];
    for (int c = wave; c < nc; c += 4) {
        const float* xp = &X[(size_t)list[c] * EMBED + lane * 16];
        float p = 0.f;
#pragma unroll
        for (int i = 0; i < 4; ++i) {
            const float4 x4 = *(const float4*)(xp + i * 4);
            p += q[i].x * x4.x + q[i].y * x4.y + q[i].z * x4.z + q[i].w * x4.w;
        }
#pragma unroll
        for (int off = 32; off >= 1; off >>= 1) p += __shfl_xor(p, off, 64);
        if (lane == 0) ll[c] = p * 0.03125f;
    }
    __syncthreads();

    // exact softmax over candidates (redundant per thread; nc is tiny)
    float mt = -3.4e38f;
    for (int c = 0; c < nc; ++c) mt = fmaxf(mt, ll[c]);
    float wsum = 0.f;
    for (int c = 0; c < nc; ++c) wsum += __expf(ll[c] - mt);
    const float inv = 1.0f / wsum;

    float4 o = {0.f, 0.f, 0.f, 0.f};
    for (int c = 0; c < nc; ++c) {
        const float w = __expf(ll[c] - mt);
        const float4 xj = *(const float4*)&X[(size_t)list[c] * EMBED + t * 4];
        o.x += w * xj.x; o.y += w * xj.y; o.z += w * xj.z; o.w += w * xj.w;
    }
    o.x *= inv; o.y *= inv; o.z *= inv; o.w *= inv;
    *(float4*)&out[(size_t)row * EMBED + t * 4] = o;
}

extern "C" void kernel_launch(void* const* d_in, const int* in_sizes, int n_in,
                              void* d_out, int out_size, void* d_ws, size_t ws_size,
                              hipStream_t stream) {
    const float* X  = (const float*)d_in[0];  // [4096,1024]
    const float* Wq = (const float*)d_in[1];  // [1024,1024]
    const float* Wk = (const float*)d_in[2];  // [1024,1024]
    float* out = (float*)d_out;

    char* ws = (char*)d_ws;
    const size_t MB = 1024 * 1024;
    unsigned short* Xhi = (unsigned short*)(ws + 0 * MB);   // 8 MB
    unsigned short* Xlo = (unsigned short*)(ws + 8 * MB);   // 8 MB
    signed char*    Xi8 = (signed char*)(ws + 16 * MB);     // 4 MB
    float*          Qf  = (float*)(ws + 20 * MB);           // 16 MB
    signed char*    Qi8 = (signed char*)(ws + 36 * MB);     // 4 MB
    float* tmax = (float*)(ws + 40 * MB);                   // 1 MB
    int*   cnts = (int*)(ws + 41 * MB);                     // 1 MB
    int2*  cand = (int2*)(ws + 42 * MB);                    // 16 MB
    unsigned short* Wqhi = (unsigned short*)(ws + 58 * MB);
    unsigned short* Wqlo = (unsigned short*)(ws + 60 * MB);
    unsigned short* Wkhi = (unsigned short*)(ws + 62 * MB);
    unsigned short* Wklo = (unsigned short*)(ws + 64 * MB);
    unsigned short* Thi  = (unsigned short*)(ws + 66 * MB);
    unsigned short* Tlo  = (unsigned short*)(ws + 68 * MB);
    // T fp32 partials (4 x 4 MB) alias the cand region: written/consumed
    // (t_fused -> t_merge) strictly before gemm_i8_scores writes cand.
    float* Tpart = (float*)(ws + 42 * MB);                  // 16 MB

    // 1) W splits only (the T GEMM's operands)
    prep_w<<<2048, 256, 0, stream>>>(
        (const float4*)Wq, (const float4*)Wk,
        (ushort4*)Wqhi, (ushort4*)Wqlo, (ushort4*)Wkhi, (ushort4*)Wklo);

    // 2) fused: split-K=4 T-partials (z<4) + X split (z>=4, overlapped)
    t_fused<<<dim3(16, 16, 20), 256, 0, stream>>>(
        Wkhi, Wklo, Wqhi, Wqlo, Tpart,
        (const float4*)X, (ushort4*)Xhi, (ushort4*)Xlo, (char4*)Xi8);

    // 3) merge partials -> split bf16 T
    t_merge<<<1024, 256, 0, stream>>>((const float4*)Tpart,
                                      (ushort4*)Thi, (ushort4*)Tlo);

    // 4) Qf = X @ T^T (= X @ M): all-bf16 global_load_lds, 8 waves, 48 KB
    qf_gemm<<<dim3(16, 32), 512, 0, stream>>>(
        Xhi, Xlo, Thi, Tlo, Qf, Qi8);

    // 5) i8 cheap scores (256x128 tile, m97 2-barrier, K-step 128)
    gemm_i8_scores<<<dim3(32, 16), 512, 0, stream>>>(Qi8, Xi8, tmax, cnts, cand);

    // 6) exact sparse softmax + gather
    sparse_out<<<NTOK, 256, 0, stream>>>(tmax, cnts, cand, Qf, X, out);
}